// Round 6
// baseline (2033.605 us; speedup 1.0000x reference)
//
#include <hip/hip_runtime.h>

typedef unsigned short u16;
typedef unsigned int u32;
typedef __attribute__((ext_vector_type(8))) _Float16 f16x8;
typedef __attribute__((ext_vector_type(4))) float f32x4;

#define U_CONST 0.999f

// ---------- byte offsets in d_ws ----------
constexpr size_t OFFB_STATS = 0;         // 3584 f32
constexpr size_t OFFB_WSTAT = 14336;     // 1024 f32
constexpr size_t OFFB_MASK  = 18432;     // 256 f32
constexpr size_t OFFB_FC7   = 19456;     // 131072 f32
constexpr size_t OFFB_FC8   = 543744;    // 131072 f32
constexpr size_t OFFB_FCIN  = 1068032;   // 1048576 f32
constexpr size_t OFFB_WT2   = 5262336;   // f16 weights [tap][co][ci]
constexpr size_t OFFB_WT3   = 5336064;
constexpr size_t OFFB_WT4   = 5483520;
constexpr size_t OFFB_WT5   = 5778432;
constexpr size_t OFFB_WT6   = 6368256;
constexpr size_t OFFB_SLAB1 = 8388608;   // conv outputs (<=33.6MB)
constexpr size_t OFFB_SLAB2 = 41943040;  // xt + padded activations (<=37.9MB)

// ---------- helpers ----------
__device__ __forceinline__ u16 f2h(float f) {
  _Float16 h = (_Float16)f;               // RTN f32->f16
  return __builtin_bit_cast(u16, h);
}
__device__ __forceinline__ float h2f(u16 u) {
  return (float)__builtin_bit_cast(_Float16, u);
}
__device__ __forceinline__ void gload16(const void* g, void* l) {
  __builtin_amdgcn_global_load_lds(
      (const __attribute__((address_space(1))) unsigned int*)g,
      (__attribute__((address_space(3))) unsigned int*)l, 16, 0, 0);
}

// ---------- layout transforms ----------
__global__ __launch_bounds__(256) void k_xform_x(const float* __restrict__ x,
                                                 float* __restrict__ xt) {
  int idx = blockIdx.x * 256 + threadIdx.x;  // 786432 total
  if (idx >= 256 * 3 * 1024) return;
  int c = idx % 3;
  int t = idx / 3;
  int s = t % 1024;
  int b = t / 1024;
  xt[idx] = x[(b * 3 + c) * 1024 + s];  // NCHW -> NHWC
}

// OIHW fp32 -> [tap][co][ci] f16
__global__ __launch_bounds__(256) void k_xform_w(const float* __restrict__ w,
                                                 u16* __restrict__ wt, int CO,
                                                 int CI) {
  int total = CO * CI * 9;
  for (int idx = blockIdx.x * 256 + threadIdx.x; idx < total;
       idx += gridDim.x * 256) {
    int ci = idx % CI;
    int t = idx / CI;
    int co = t % CO;
    int tap = t / CO;
    wt[idx] = f2h(w[(co * CI + ci) * 9 + tap]);
  }
}

// ---------- conv1 (CIN=3), fp32 math, f16 out ----------
__global__ __launch_bounds__(256) void k_conv1(const float* __restrict__ xt,
                                               const float* __restrict__ w1,
                                               const float* __restrict__ b1,
                                               u16* __restrict__ y) {
  __shared__ float Ins[4 * 34 * 3];
  __shared__ float Ws[27 * 64];
  int tid = threadIdx.x;
  int m0 = blockIdx.x * 64;
  int b = m0 >> 10;
  int y0 = (m0 & 1023) >> 5;

  for (int i = tid; i < 27 * 64; i += 256) {
    int co = i & 63;
    int t = i >> 6;
    int ci = t % 3;
    int tap = t / 3;
    Ws[i] = w1[co * 27 + ci * 9 + tap];
  }
  for (int i = tid; i < 4 * 34 * 3; i += 256) {
    int ci = i % 3;
    int t = i / 3;
    int xx = t % 34;
    int yy = t / 34;
    int gy = y0 - 1 + yy;
    int gx = xx - 1;
    float v = 0.f;
    if ((unsigned)gy < 32u && (unsigned)gx < 32u)
      v = xt[((b * 32 + gy) * 32 + gx) * 3 + ci];
    Ins[i] = v;
  }
  __syncthreads();

  int tr = tid >> 4, tc = tid & 15;
  float acc[4][4] = {};
#pragma unroll
  for (int tap = 0; tap < 9; tap++) {
    int dy = tap / 3, dx = tap % 3;
#pragma unroll
    for (int ci = 0; ci < 3; ci++) {
      float4 wv = *(const float4*)&Ws[(tap * 3 + ci) * 64 + tc * 4];
#pragma unroll
      for (int i = 0; i < 4; i++) {
        int r = tr * 4 + i;
        int yy = (r >> 5) + dy;
        int xx = (r & 31) + dx;
        float a = Ins[(yy * 34 + xx) * 3 + ci];
        acc[i][0] += a * wv.x;
        acc[i][1] += a * wv.y;
        acc[i][2] += a * wv.z;
        acc[i][3] += a * wv.w;
      }
    }
  }
  float4 bb = *(const float4*)&b1[tc * 4];
#pragma unroll
  for (int i = 0; i < 4; i++) {
    size_t r = (size_t)(m0 + tr * 4 + i);
    u32 lo = (u32)f2h(acc[i][0] + bb.x) | ((u32)f2h(acc[i][1] + bb.y) << 16);
    u32 hi = (u32)f2h(acc[i][2] + bb.z) | ((u32)f2h(acc[i][3] + bb.w) << 16);
    *(uint2*)&y[r * 64 + tc * 4] = make_uint2(lo, hi);
  }
}

// ---------- f16 MFMA implicit-GEMM 3x3 conv ----------
// in: padded NHWC f16 [256][H+2][W+2][CIN]; wt: [9][COUT][CIN] f16
// out: [256*H*W][COUT] f16 (= conv + bias, optionally * mask[n])
template <int CIN, int COUT, int H, int W, bool MASKED>
__global__ __launch_bounds__(256) void k_cmfma(
    const u16* __restrict__ inp, const u16* __restrict__ wt,
    const float* __restrict__ bias, const float* __restrict__ mask,
    u16* __restrict__ out) {
  constexpr int HW = H * W;
  __shared__ __align__(16) u16 ldsA[128 * 64];
  __shared__ __align__(16) u16 ldsB[64 * 64];
  const int tid = threadIdx.x;
  const int wave = tid >> 6, lane = tid & 63;
  const int m0 = blockIdx.x * 128;
  const int n0 = blockIdx.y * 64;
  // staging: lane -> dest row (lane>>3), dest slot (lane&7); source slot is
  // XOR-swizzled so the linear global_load_lds dest + swizzled ds_read agree.
  const int ss = (lane & 7) ^ (lane >> 3);
  const u16* aptr[4];
#pragma unroll
  for (int q = 0; q < 4; q++) {
    int m = m0 + wave * 32 + q * 8 + (lane >> 3);
    int b = m / HW, rem = m % HW;
    int yy = rem / W, xx = rem % W;
    aptr[q] = inp +
              ((size_t)((b * (H + 2) + yy + 1) * (W + 2)) + xx + 1) * CIN +
              ss * 8;
  }
  const u16* bptr[2];
#pragma unroll
  for (int q = 0; q < 2; q++) {
    int rb = wave * 16 + q * 8 + (lane >> 3);
    bptr[q] = wt + (size_t)(n0 + rb) * CIN + ss * 8;
  }
  u16* lA = ldsA + wave * 32 * 64;
  u16* lB = ldsB + wave * 16 * 64;
  const int arow0 = wave * 32 + (lane & 15);
  const int nrow = lane & 15;
  const int t0 = lane >> 4, x7 = lane & 7;
  f32x4 acc[2][4] = {};

#pragma unroll 1
  for (int tap = 0; tap < 9; tap++) {
    const int aoff = (tap / 3 - 1) * ((W + 2) * CIN) + (tap % 3 - 1) * CIN;
    const size_t woff = (size_t)tap * COUT * CIN;
#pragma unroll 1
    for (int c0 = 0; c0 < CIN; c0 += 64) {
      __syncthreads();  // previous compute done before LDS overwrite
#pragma unroll
      for (int q = 0; q < 4; q++) gload16(aptr[q] + aoff + c0, lA + q * 512);
#pragma unroll
      for (int q = 0; q < 2; q++) gload16(bptr[q] + woff + c0, lB + q * 512);
      __syncthreads();  // compiler drains vmcnt before barrier -> tiles ready
#pragma unroll
      for (int h = 0; h < 2; h++) {
        const int sl = (((h << 2) + t0) ^ x7) * 8;
        f16x8 af[2], bf[4];
#pragma unroll
        for (int i = 0; i < 2; i++)
          af[i] = *(const f16x8*)&ldsA[(arow0 + i * 16) * 64 + sl];
#pragma unroll
        for (int j = 0; j < 4; j++)
          bf[j] = *(const f16x8*)&ldsB[(nrow + j * 16) * 64 + sl];
#pragma unroll
        for (int i = 0; i < 2; i++)
#pragma unroll
          for (int j = 0; j < 4; j++)
            acc[i][j] = __builtin_amdgcn_mfma_f32_16x16x32_f16(
                af[i], bf[j], acc[i][j], 0, 0, 0);
      }
    }
  }
  float bn[4], mk[4];
#pragma unroll
  for (int j = 0; j < 4; j++) {
    int n = n0 + j * 16 + nrow;
    bn[j] = bias[n];
    mk[j] = MASKED ? mask[n] : 1.f;
  }
#pragma unroll
  for (int i = 0; i < 2; i++)
#pragma unroll
    for (int r = 0; r < 4; r++) {
      int m = m0 + wave * 32 + i * 16 + (lane >> 4) * 4 + r;
#pragma unroll
      for (int j = 0; j < 4; j++) {
        float v = acc[i][j][r] + bn[j];
        if (MASKED) v *= mk[j];
        out[(size_t)m * COUT + n0 + j * 16 + nrow] = f2h(v);
      }
    }
}

// ---------- per-channel sum/sumsq over f16 NHWC buffer ----------
template <int C>
__global__ __launch_bounds__(256) void k_bnstat(const u16* __restrict__ y,
                                                size_t T,  // uint4 count
                                                float* __restrict__ stats) {
  constexpr int CH8 = C / 8;
  int tid = threadIdx.x;
  float s[8] = {}, ss[8] = {};
  for (size_t i = (size_t)blockIdx.x * 256 + tid; i < T;
       i += (size_t)gridDim.x * 256) {
    uint4 v = ((const uint4*)y)[i];
    u32 pv[4] = {v.x, v.y, v.z, v.w};
#pragma unroll
    for (int k = 0; k < 4; k++) {
      float lo = h2f((u16)(pv[k] & 0xffffu));
      float hi = h2f((u16)(pv[k] >> 16));
      s[2 * k] += lo;
      ss[2 * k] += lo * lo;
      s[2 * k + 1] += hi;
      ss[2 * k + 1] += hi * hi;
    }
  }
#pragma unroll
  for (int off = CH8; off < 64; off <<= 1) {
#pragma unroll
    for (int j = 0; j < 8; j++) {
      s[j] += __shfl_down(s[j], off);
      ss[j] += __shfl_down(ss[j], off);
    }
  }
  __shared__ float red[4][CH8][16];
  int wave = tid >> 6, lane = tid & 63;
  if (lane < CH8) {
#pragma unroll
    for (int j = 0; j < 8; j++) {
      red[wave][lane][j] = s[j];
      red[wave][lane][8 + j] = ss[j];
    }
  }
  __syncthreads();
  if (tid < CH8) {
#pragma unroll
    for (int j = 0; j < 8; j++) {
      float a = 0.f, b = 0.f;
#pragma unroll
      for (int w = 0; w < 4; w++) {
        a += red[w][tid][j];
        b += red[w][tid][8 + j];
      }
      int c = tid * 8 + j;
      atomicAdd(&stats[c * 2], a);
      atomicAdd(&stats[c * 2 + 1], b);
    }
  }
}

// ---------- BN affine + relu, write zero-padded f16 buffer ----------
template <int C, int H, int W>
__global__ __launch_bounds__(256) void k_bnrelu_pad(
    const u16* __restrict__ y, float invN, const float* __restrict__ st,
    const float* __restrict__ g, const float* __restrict__ be,
    u16* __restrict__ outp) {
  constexpr int CH8 = C / 8, HP = H + 2, WP = W + 2;
  __shared__ float sA[C], sB[C];
  int tid = threadIdx.x;
  if (tid < C) {
    float mu = st[tid * 2] * invN;
    float var = st[tid * 2 + 1] * invN - mu * mu;
    float sc = g[tid] * rsqrtf(var + 1e-5f);
    sA[tid] = sc;
    sB[tid] = be[tid] - mu * sc;
  }
  __syncthreads();
  const size_t T = (size_t)256 * HP * WP * CH8;
  for (size_t i = (size_t)blockIdx.x * 256 + tid; i < T;
       i += (size_t)gridDim.x * 256) {
    int slot = (int)(i % CH8);
    size_t t = i / CH8;
    int xx = (int)(t % WP);
    t /= WP;
    int yy = (int)(t % HP);
    int b = (int)(t / HP);
    uint4 o;
    if (yy == 0 || yy == HP - 1 || xx == 0 || xx == WP - 1) {
      o = make_uint4(0u, 0u, 0u, 0u);
    } else {
      uint4 v =
          ((const uint4*)y)[(((size_t)(b * H + yy - 1) * W) + xx - 1) * CH8 +
                            slot];
      u32 pv[4] = {v.x, v.y, v.z, v.w};
      u32 po[4];
      int c0 = slot * 8;
#pragma unroll
      for (int k = 0; k < 4; k++) {
        int c = c0 + 2 * k;
        float lo = fmaxf(h2f((u16)(pv[k] & 0xffffu)) * sA[c] + sB[c], 0.f);
        float hi =
            fmaxf(h2f((u16)(pv[k] >> 16)) * sA[c + 1] + sB[c + 1], 0.f);
        po[k] = (u32)f2h(lo) | ((u32)f2h(hi) << 16);
      }
      o = make_uint4(po[0], po[1], po[2], po[3]);
    }
    ((uint4*)outp)[i] = o;
  }
}

// ---------- BN affine + relu + 2x2 maxpool ----------
// NCHW=false: write zero-padded f16 (HO+2, WO+2). NCHW=true: fp32 NCHW flat.
template <int C, int H, int W, bool NCHW>
__global__ __launch_bounds__(256) void k_bnpool(
    const u16* __restrict__ y, float invN, const float* __restrict__ st,
    const float* __restrict__ g, const float* __restrict__ be,
    void* __restrict__ outv) {
  constexpr int CH8 = C / 8, HO = H / 2, WO = W / 2;
  constexpr int HP = NCHW ? HO : HO + 2, WP = NCHW ? WO : WO + 2;
  __shared__ float sA[C], sB[C];
  int tid = threadIdx.x;
  if (tid < C) {
    float mu = st[tid * 2] * invN;
    float var = st[tid * 2 + 1] * invN - mu * mu;
    float sc = g[tid] * rsqrtf(var + 1e-5f);
    sA[tid] = sc;
    sB[tid] = be[tid] - mu * sc;
  }
  __syncthreads();
  const size_t T = (size_t)256 * HP * WP * CH8;
  for (size_t i = (size_t)blockIdx.x * 256 + tid; i < T;
       i += (size_t)gridDim.x * 256) {
    int slot = (int)(i % CH8);
    size_t t = i / CH8;
    int xx = (int)(t % WP);
    t /= WP;
    int yy = (int)(t % HP);
    int b = (int)(t / HP);
    int px, py;
    bool border = false;
    if (NCHW) {
      px = xx;
      py = yy;
    } else {
      px = xx - 1;
      py = yy - 1;
      border = (yy == 0 || yy == HP - 1 || xx == 0 || xx == WP - 1);
    }
    if (border) {
      ((uint4*)outv)[i] = make_uint4(0u, 0u, 0u, 0u);
      continue;
    }
    const uint4* yp = (const uint4*)y;
    size_t i00 = (((size_t)(b * H + 2 * py) * W) + 2 * px) * CH8 + slot;
    uint4 v00 = yp[i00], v01 = yp[i00 + CH8];
    uint4 v10 = yp[i00 + (size_t)W * CH8], v11 = yp[i00 + (size_t)W * CH8 + CH8];
    u32 p00[4] = {v00.x, v00.y, v00.z, v00.w};
    u32 p01[4] = {v01.x, v01.y, v01.z, v01.w};
    u32 p10[4] = {v10.x, v10.y, v10.z, v10.w};
    u32 p11[4] = {v11.x, v11.y, v11.z, v11.w};
    int c0 = slot * 8;
    float r[8];
#pragma unroll
    for (int k = 0; k < 4; k++) {
      int c = c0 + 2 * k;
      float a_ = sA[c], b_ = sB[c], a2 = sA[c + 1], b2 = sB[c + 1];
      float l0 = fmaxf(h2f((u16)(p00[k] & 0xffffu)) * a_ + b_, 0.f);
      float l1 = fmaxf(h2f((u16)(p01[k] & 0xffffu)) * a_ + b_, 0.f);
      float l2 = fmaxf(h2f((u16)(p10[k] & 0xffffu)) * a_ + b_, 0.f);
      float l3 = fmaxf(h2f((u16)(p11[k] & 0xffffu)) * a_ + b_, 0.f);
      float h0 = fmaxf(h2f((u16)(p00[k] >> 16)) * a2 + b2, 0.f);
      float h1 = fmaxf(h2f((u16)(p01[k] >> 16)) * a2 + b2, 0.f);
      float h2 = fmaxf(h2f((u16)(p10[k] >> 16)) * a2 + b2, 0.f);
      float h3 = fmaxf(h2f((u16)(p11[k] >> 16)) * a2 + b2, 0.f);
      r[2 * k] = fmaxf(fmaxf(l0, l1), fmaxf(l2, l3));
      r[2 * k + 1] = fmaxf(fmaxf(h0, h1), fmaxf(h2, h3));
    }
    if (NCHW) {
      float* of = (float*)outv;
#pragma unroll
      for (int j = 0; j < 8; j++)
        of[((size_t)(b * C + c0 + j) * HO + py) * WO + px] = r[j];
    } else {
      u32 po[4];
#pragma unroll
      for (int k = 0; k < 4; k++)
        po[k] = (u32)f2h(r[2 * k]) | ((u32)f2h(r[2 * k + 1]) << 16);
      ((uint4*)outv)[i] = make_uint4(po[0], po[1], po[2], po[3]);
    }
  }
}

// ---------- FC GEMM fp32: out(256,N) = a(256,K) @ w(N,K)^T + bias ----------
template <int K, int N>
__global__ __launch_bounds__(256) void k_fc(const float* __restrict__ a,
                                            const float* __restrict__ w,
                                            const float* __restrict__ bias,
                                            float* __restrict__ out) {
  __shared__ float As[32][68], Bs[32][68];
  int tid = threadIdx.x;
  int m0 = blockIdx.x * 64, n0 = blockIdx.y * 64;
  int lrow = tid >> 2, lq = tid & 3;
  int ln = tid & 63, kq = tid >> 6;
  int tr = tid >> 4, tc = tid & 15;
  float acc[4][4] = {};
  for (int c0 = 0; c0 < K; c0 += 32) {
    float4 va0 = *(const float4*)(a + (size_t)(m0 + lrow) * K + c0 + lq * 4);
    float4 va1 =
        *(const float4*)(a + (size_t)(m0 + lrow) * K + c0 + lq * 4 + 16);
    float4 vb0 = *(const float4*)(w + (size_t)(n0 + ln) * K + c0 + kq * 8);
    float4 vb1 = *(const float4*)(w + (size_t)(n0 + ln) * K + c0 + kq * 8 + 4);
    __syncthreads();
    As[lq * 4 + 0][lrow] = va0.x;
    As[lq * 4 + 1][lrow] = va0.y;
    As[lq * 4 + 2][lrow] = va0.z;
    As[lq * 4 + 3][lrow] = va0.w;
    As[lq * 4 + 16][lrow] = va1.x;
    As[lq * 4 + 17][lrow] = va1.y;
    As[lq * 4 + 18][lrow] = va1.z;
    As[lq * 4 + 19][lrow] = va1.w;
    Bs[kq * 8 + 0][ln] = vb0.x;
    Bs[kq * 8 + 1][ln] = vb0.y;
    Bs[kq * 8 + 2][ln] = vb0.z;
    Bs[kq * 8 + 3][ln] = vb0.w;
    Bs[kq * 8 + 4][ln] = vb1.x;
    Bs[kq * 8 + 5][ln] = vb1.y;
    Bs[kq * 8 + 6][ln] = vb1.z;
    Bs[kq * 8 + 7][ln] = vb1.w;
    __syncthreads();
#pragma unroll
    for (int k = 0; k < 32; k++) {
      float4 av = *(const float4*)&As[k][tr * 4];
      float4 bv = *(const float4*)&Bs[k][tc * 4];
      acc[0][0] += av.x * bv.x; acc[0][1] += av.x * bv.y;
      acc[0][2] += av.x * bv.z; acc[0][3] += av.x * bv.w;
      acc[1][0] += av.y * bv.x; acc[1][1] += av.y * bv.y;
      acc[1][2] += av.y * bv.z; acc[1][3] += av.y * bv.w;
      acc[2][0] += av.z * bv.x; acc[2][1] += av.z * bv.y;
      acc[2][2] += av.z * bv.z; acc[2][3] += av.z * bv.w;
      acc[3][0] += av.w * bv.x; acc[3][1] += av.w * bv.y;
      acc[3][2] += av.w * bv.z; acc[3][3] += av.w * bv.w;
    }
  }
  float4 bb = *(const float4*)&bias[n0 + tc * 4];
#pragma unroll
  for (int i = 0; i < 4; i++) {
    float4 o;
    o.x = acc[i][0] + bb.x;
    o.y = acc[i][1] + bb.y;
    o.z = acc[i][2] + bb.z;
    o.w = acc[i][3] + bb.w;
    *(float4*)&out[(size_t)(m0 + tr * 4 + i) * N + n0 + tc * 4] = o;
  }
}

// ---------- BN1d (+relu) in place ----------
template <int N>
__global__ __launch_bounds__(256) void k_bn1drelu(float* __restrict__ x,
                                                  const float* __restrict__ g,
                                                  const float* __restrict__ be) {
  int c = blockIdx.x * 256 + threadIdx.x;
  if (c >= N) return;
  float s = 0.f, ss = 0.f;
  for (int r = 0; r < 256; r++) {
    float v = x[(size_t)r * N + c];
    s += v;
    ss += v * v;
  }
  float mu = s * (1.f / 256.f);
  float var = ss * (1.f / 256.f) - mu * mu;
  float sc = g[c] * rsqrtf(var + 1e-5f);
  float sh = be[c] - mu * sc;
  for (int r = 0; r < 256; r++) {
    float v = x[(size_t)r * N + c] * sc + sh;
    x[(size_t)r * N + c] = v > 0.f ? v : 0.f;
  }
}

// ---------- fc9 ----------
__global__ __launch_bounds__(256) void k_fc9(const float* __restrict__ a,
                                             const float* __restrict__ w,
                                             const float* __restrict__ bias,
                                             float* __restrict__ out) {
  int b = blockIdx.x, tid = threadIdx.x;
  int o = tid & 15, ch = tid >> 4;
  float s = 0.f;
  if (o < 10) {
    const float* ap = a + (size_t)b * 512 + ch * 32;
    const float* wp = w + (size_t)o * 512 + ch * 32;
#pragma unroll
    for (int k = 0; k < 32; k++) s += ap[k] * wp[k];
  }
  __shared__ float red[16][17];
  red[ch][o] = s;
  __syncthreads();
  if (tid < 10) {
    float t = bias[tid];
#pragma unroll
    for (int c2 = 0; c2 < 16; c2++) t += red[c2][tid];
    out[b * 10 + tid] = t;
  }
}

// ---------- ALSH: per-filter sumsq + hash dots ----------
__global__ __launch_bounds__(256) void k_w6stats(const float* __restrict__ w6,
                                                 const float* __restrict__ ha,
                                                 float* __restrict__ wstats) {
  int f = blockIdx.x, tid = threadIdx.x;
  const float* wp = w6 + (size_t)f * 2304;
  float ss = 0.f, d0 = 0.f, d1 = 0.f;
#pragma unroll
  for (int k = 0; k < 9; k++) {
    float v = wp[k * 256 + tid];
    ss += v * v;
    d0 += v * ha[k * 256 + tid];
    d1 += v * ha[2306 + k * 256 + tid];
  }
  for (int off = 32; off > 0; off >>= 1) {
    ss += __shfl_down(ss, off);
    d0 += __shfl_down(d0, off);
    d1 += __shfl_down(d1, off);
  }
  __shared__ float r[4][3];
  int wv = tid >> 6, ln = tid & 63;
  if (ln == 0) {
    r[wv][0] = ss;
    r[wv][1] = d0;
    r[wv][2] = d1;
  }
  __syncthreads();
  if (tid == 0) {
    float a0 = 0.f, a1 = 0.f, a2 = 0.f;
    for (int i = 0; i < 4; i++) {
      a0 += r[i][0];
      a1 += r[i][1];
      a2 += r[i][2];
    }
    wstats[f * 4 + 0] = a0;
    wstats[f * 4 + 1] = a1;
    wstats[f * 4 + 2] = a2;
  }
}

// ---------- ALSH: final mask ----------
__global__ __launch_bounds__(256) void k_mask(const float* __restrict__ wstats,
                                              const float* __restrict__ qstats,
                                              const float* __restrict__ ha,
                                              float invN,
                                              float* __restrict__ mask) {
  int tid = threadIdx.x;
  __shared__ float red[256];
  float n2 = wstats[tid * 4];
  red[tid] = n2;
  __syncthreads();
  for (int off = 128; off > 0; off >>= 1) {
    if (tid < off) red[tid] = fmaxf(red[tid], red[tid + off]);
    __syncthreads();
  }
  float maxn2 = red[0];
  float qm = qstats[tid * 2] * invN;
  float h0 = 0.f, h1 = 0.f;
#pragma unroll
  for (int k = 0; k < 9; k++) {
    h0 += ha[k * 256 + tid];
    h1 += ha[2306 + k * 256 + tid];
  }
  __shared__ float r0[256], r1[256];
  r0[tid] = qm * h0;
  r1[tid] = qm * h1;
  __syncthreads();
  for (int off = 128; off > 0; off >>= 1) {
    if (tid < off) {
      r0[tid] += r0[tid + off];
      r1[tid] += r1[tid + off];
    }
    __syncthreads();
  }
  float qd0 = r0[0], qd1 = r1[0];
  float s = U_CONST / sqrtf(maxn2);
  float ns2 = s * s * wstats[tid * 4];
  float v0 = s * wstats[tid * 4 + 1] + ns2 * ha[2304] + ns2 * ns2 * ha[2305];
  float v1 = s * wstats[tid * 4 + 2] + ns2 * ha[2306 + 2304] +
             ns2 * ns2 * ha[2306 + 2305];
  bool bf0 = v0 > 0.f, bf1 = v1 > 0.f;
  bool bq0 = qd0 > 0.f, bq1 = qd1 > 0.f;
  mask[tid] = (bf0 == bq0 && bf1 == bq1) ? 1.f : 0.f;
}

// ======================================================================
extern "C" void kernel_launch(void* const* d_in, const int* in_sizes, int n_in,
                              void* d_out, int out_size, void* d_ws,
                              size_t ws_size, hipStream_t stream) {
  (void)in_sizes; (void)n_in; (void)out_size; (void)ws_size;
  const float* x = (const float*)d_in[0];
  const float* w1 = (const float*)d_in[1];
  const float* b1 = (const float*)d_in[2];
  const float* g1 = (const float*)d_in[3];
  const float* be1 = (const float*)d_in[4];
  const float* w2 = (const float*)d_in[5];
  const float* b2 = (const float*)d_in[6];
  const float* g2 = (const float*)d_in[7];
  const float* be2 = (const float*)d_in[8];
  const float* w3 = (const float*)d_in[9];
  const float* b3 = (const float*)d_in[10];
  const float* g3 = (const float*)d_in[11];
  const float* be3 = (const float*)d_in[12];
  const float* w4 = (const float*)d_in[13];
  const float* b4 = (const float*)d_in[14];
  const float* g4 = (const float*)d_in[15];
  const float* be4 = (const float*)d_in[16];
  const float* w5 = (const float*)d_in[17];
  const float* b5 = (const float*)d_in[18];
  const float* g5 = (const float*)d_in[19];
  const float* be5 = (const float*)d_in[20];
  const float* w6 = (const float*)d_in[21];
  const float* b6 = (const float*)d_in[22];
  const float* g6 = (const float*)d_in[23];
  const float* be6 = (const float*)d_in[24];
  const float* hash_a = (const float*)d_in[25];
  const float* fc7_w = (const float*)d_in[26];
  const float* fc7_b = (const float*)d_in[27];
  const float* g7 = (const float*)d_in[28];
  const float* be7 = (const float*)d_in[29];
  const float* fc8_w = (const float*)d_in[30];
  const float* fc8_b = (const float*)d_in[31];
  const float* g8 = (const float*)d_in[32];
  const float* be8 = (const float*)d_in[33];
  const float* fc9_w = (const float*)d_in[34];
  const float* fc9_b = (const float*)d_in[35];

  char* wsb = (char*)d_ws;
  float* stats = (float*)(wsb + OFFB_STATS);
  float* wstats = (float*)(wsb + OFFB_WSTAT);
  float* maskb = (float*)(wsb + OFFB_MASK);
  float* fc7o = (float*)(wsb + OFFB_FC7);
  float* fc8o = (float*)(wsb + OFFB_FC8);
  float* fcin = (float*)(wsb + OFFB_FCIN);
  u16* wt2 = (u16*)(wsb + OFFB_WT2);
  u16* wt3 = (u16*)(wsb + OFFB_WT3);
  u16* wt4 = (u16*)(wsb + OFFB_WT4);
  u16* wt5 = (u16*)(wsb + OFFB_WT5);
  u16* wt6 = (u16*)(wsb + OFFB_WT6);
  u16* slab1 = (u16*)(wsb + OFFB_SLAB1);   // conv outputs
  u16* slab2 = (u16*)(wsb + OFFB_SLAB2);   // xt, then padded activations
  float* xt = (float*)(wsb + OFFB_SLAB2);
  float* outp = (float*)d_out;

  hipMemsetAsync(stats, 0, 3584 * sizeof(float), stream);

  k_xform_x<<<3072, 256, 0, stream>>>(x, xt);
  k_xform_w<<<144, 256, 0, stream>>>(w2, wt2, 64, 64);
  k_xform_w<<<288, 256, 0, stream>>>(w3, wt3, 128, 64);
  k_xform_w<<<576, 256, 0, stream>>>(w4, wt4, 128, 128);
  k_xform_w<<<1152, 256, 0, stream>>>(w5, wt5, 256, 128);
  k_xform_w<<<2304, 256, 0, stream>>>(w6, wt6, 256, 256);
  k_w6stats<<<256, 256, 0, stream>>>(w6, hash_a, wstats);

  // layer 1: conv(3->64)@32x32 (fp32 math, f16 out)
  k_conv1<<<4096, 256, 0, stream>>>(xt, w1, b1, slab1);
  k_bnstat<64><<<512, 256, 0, stream>>>(slab1, (size_t)2097152, stats + 0);
  k_bnrelu_pad<64, 32, 32><<<1024, 256, 0, stream>>>(
      slab1, 1.f / 262144.f, stats + 0, g1, be1, slab2);
  // layer 2: conv(64->64)@32x32, pool -> pad 16x16
  k_cmfma<64, 64, 32, 32, false><<<dim3(2048, 1), 256, 0, stream>>>(
      slab2, wt2, b2, nullptr, slab1);
  k_bnstat<64><<<512, 256, 0, stream>>>(slab1, (size_t)2097152, stats + 512);
  k_bnpool<64, 32, 32, false><<<512, 256, 0, stream>>>(
      slab1, 1.f / 262144.f, stats + 512, g2, be2, slab2);
  // layer 3: conv(64->128)@16x16
  k_cmfma<64, 128, 16, 16, false><<<dim3(512, 2), 256, 0, stream>>>(
      slab2, wt3, b3, nullptr, slab1);
  k_bnstat<128><<<512, 256, 0, stream>>>(slab1, (size_t)1048576, stats + 1024);
  k_bnrelu_pad<128, 16, 16><<<1024, 256, 0, stream>>>(
      slab1, 1.f / 65536.f, stats + 1024, g3, be3, slab2);
  // layer 4: conv(128->128)@16x16, pool -> pad 8x8
  k_cmfma<128, 128, 16, 16, false><<<dim3(512, 2), 256, 0, stream>>>(
      slab2, wt4, b4, nullptr, slab1);
  k_bnstat<128><<<512, 256, 0, stream>>>(slab1, (size_t)1048576, stats + 1536);
  k_bnpool<128, 16, 16, false><<<512, 256, 0, stream>>>(
      slab1, 1.f / 65536.f, stats + 1536, g4, be4, slab2);
  // layer 5: conv(128->256)@8x8
  k_cmfma<128, 256, 8, 8, false><<<dim3(128, 4), 256, 0, stream>>>(
      slab2, wt5, b5, nullptr, slab1);
  k_bnstat<256><<<512, 256, 0, stream>>>(slab1, (size_t)524288, stats + 2048);
  k_bnrelu_pad<256, 8, 8><<<1024, 256, 0, stream>>>(
      slab1, 1.f / 16384.f, stats + 2048, g5, be5, slab2);
  // ALSH mask from a5 (padded buffer; zero borders don't affect the sum)
  k_bnstat<256><<<512, 256, 0, stream>>>(slab2, (size_t)819200, stats + 3072);
  k_mask<<<1, 256, 0, stream>>>(wstats, stats + 3072, hash_a, 1.f / 16384.f,
                                maskb);
  // layer 6: conv(256->256)@8x8 masked, pool -> NCHW fp32 flat
  k_cmfma<256, 256, 8, 8, true><<<dim3(128, 4), 256, 0, stream>>>(
      slab2, wt6, b6, maskb, slab1);
  k_bnstat<256><<<512, 256, 0, stream>>>(slab1, (size_t)524288, stats + 2560);
  k_bnpool<256, 8, 8, true><<<512, 256, 0, stream>>>(
      slab1, 1.f / 16384.f, stats + 2560, g6, be6, fcin);
  // FC head (fp32)
  k_fc<4096, 512><<<dim3(4, 8), 256, 0, stream>>>(fcin, fc7_w, fc7_b, fc7o);
  k_bn1drelu<512><<<2, 256, 0, stream>>>(fc7o, g7, be7);
  k_fc<512, 512><<<dim3(4, 8), 256, 0, stream>>>(fc7o, fc8_w, fc8_b, fc8o);
  k_bn1drelu<512><<<2, 256, 0, stream>>>(fc8o, g8, be8);
  k_fc9<<<256, 256, 0, stream>>>(fc8o, fc9_w, fc9_b, outp);
}

// Round 7
// 1798.064 us; speedup vs baseline: 1.1310x; 1.1310x over previous
//
#include <hip/hip_runtime.h>

typedef unsigned short u16;
typedef unsigned int u32;
typedef __attribute__((ext_vector_type(8))) _Float16 f16x8;
typedef __attribute__((ext_vector_type(4))) float f32x4;

#define U_CONST 0.999f

// ---------- byte offsets in d_ws (ws_size >= ~143MB known-good from r1) ----
constexpr size_t OFFB_STATS = 0;          // 3584 f32
constexpr size_t OFFB_WSTAT = 14336;      // 256*4 f32
constexpr size_t OFFB_MASK  = 18432;      // 256 f32
constexpr size_t OFFB_FCIN  = 32768;      // f16 [256][4096] = 2MB
constexpr size_t OFFB_W7T   = 2129920;    // f16 [512][4096] = 4MB
constexpr size_t OFFB_W8T   = 6324224;    // f16 [512][512]  = 0.5MB
constexpr size_t OFFB_P7    = 6848512;    // f32 [16][256][512] = 8MB
constexpr size_t OFFB_P8    = 15237120;   // f32 [8][256][512]  = 4MB
constexpr size_t OFFB_A7    = 19431424;   // f16 [256][512]
constexpr size_t OFFB_A8    = 19693568;   // f16 [256][512]
constexpr size_t OFFB_WT2   = 20971520;   // f16 conv weights [tap][co][ci]
constexpr size_t OFFB_WT3   = 21045248;
constexpr size_t OFFB_WT4   = 21192704;
constexpr size_t OFFB_WT5   = 21487616;
constexpr size_t OFFB_WT6   = 22077440;
constexpr size_t OFFB_SLAB1 = 25165824;   // conv outputs (<=33.6MB)
constexpr size_t OFFB_SLAB2 = 60817408;   // xt + padded activations (<=38MB)

// ---------- helpers ----------
__device__ __forceinline__ u16 f2h(float f) {
  _Float16 h = (_Float16)f;
  return __builtin_bit_cast(u16, h);
}
__device__ __forceinline__ float h2f(u16 u) {
  return (float)__builtin_bit_cast(_Float16, u);
}
__device__ __forceinline__ void gload16(const void* g, void* l) {
  __builtin_amdgcn_global_load_lds(
      (const __attribute__((address_space(1))) unsigned int*)g,
      (__attribute__((address_space(3))) unsigned int*)l, 16, 0, 0);
}

// ---------- layout transforms ----------
__global__ __launch_bounds__(256) void k_xform_x(const float* __restrict__ x,
                                                 float* __restrict__ xt) {
  int idx = blockIdx.x * 256 + threadIdx.x;
  if (idx >= 256 * 3 * 1024) return;
  int c = idx % 3;
  int t = idx / 3;
  int s = t % 1024;
  int b = t / 1024;
  xt[idx] = x[(b * 3 + c) * 1024 + s];
}

__global__ __launch_bounds__(256) void k_xform_w(const float* __restrict__ w,
                                                 u16* __restrict__ wt, int CO,
                                                 int CI) {
  int total = CO * CI * 9;
  for (int idx = blockIdx.x * 256 + threadIdx.x; idx < total;
       idx += gridDim.x * 256) {
    int ci = idx % CI;
    int t = idx / CI;
    int co = t % CO;
    int tap = t / CO;
    wt[idx] = f2h(w[(co * CI + ci) * 9 + tap]);
  }
}

__global__ __launch_bounds__(256) void k_cvt_h(const float* __restrict__ w,
                                               u16* __restrict__ o, int n) {
  for (int i = blockIdx.x * 256 + threadIdx.x; i < n; i += gridDim.x * 256)
    o[i] = f2h(w[i]);
}

// ---------- conv1 (CIN=3), fp32 math, f16 out ----------
__global__ __launch_bounds__(256) void k_conv1(const float* __restrict__ xt,
                                               const float* __restrict__ w1,
                                               const float* __restrict__ b1,
                                               u16* __restrict__ y) {
  __shared__ float Ins[4 * 34 * 3];
  __shared__ float Ws[27 * 64];
  int tid = threadIdx.x;
  int m0 = blockIdx.x * 64;
  int b = m0 >> 10;
  int y0 = (m0 & 1023) >> 5;

  for (int i = tid; i < 27 * 64; i += 256) {
    int co = i & 63;
    int t = i >> 6;
    int ci = t % 3;
    int tap = t / 3;
    Ws[i] = w1[co * 27 + ci * 9 + tap];
  }
  for (int i = tid; i < 4 * 34 * 3; i += 256) {
    int ci = i % 3;
    int t = i / 3;
    int xx = t % 34;
    int yy = t / 34;
    int gy = y0 - 1 + yy;
    int gx = xx - 1;
    float v = 0.f;
    if ((unsigned)gy < 32u && (unsigned)gx < 32u)
      v = xt[((b * 32 + gy) * 32 + gx) * 3 + ci];
    Ins[i] = v;
  }
  __syncthreads();

  int tr = tid >> 4, tc = tid & 15;
  float acc[4][4] = {};
#pragma unroll
  for (int tap = 0; tap < 9; tap++) {
    int dy = tap / 3, dx = tap % 3;
#pragma unroll
    for (int ci = 0; ci < 3; ci++) {
      float4 wv = *(const float4*)&Ws[(tap * 3 + ci) * 64 + tc * 4];
#pragma unroll
      for (int i = 0; i < 4; i++) {
        int r = tr * 4 + i;
        int yy = (r >> 5) + dy;
        int xx = (r & 31) + dx;
        float a = Ins[(yy * 34 + xx) * 3 + ci];
        acc[i][0] += a * wv.x;
        acc[i][1] += a * wv.y;
        acc[i][2] += a * wv.z;
        acc[i][3] += a * wv.w;
      }
    }
  }
  float4 bb = *(const float4*)&b1[tc * 4];
#pragma unroll
  for (int i = 0; i < 4; i++) {
    size_t r = (size_t)(m0 + tr * 4 + i);
    u32 lo = (u32)f2h(acc[i][0] + bb.x) | ((u32)f2h(acc[i][1] + bb.y) << 16);
    u32 hi = (u32)f2h(acc[i][2] + bb.z) | ((u32)f2h(acc[i][3] + bb.w) << 16);
    *(uint2*)&y[r * 64 + tc * 4] = make_uint2(lo, hi);
  }
}

// ---------- f16 MFMA implicit-GEMM 3x3 conv ----------
template <int CIN, int COUT, int H, int W, bool MASKED>
__global__ __launch_bounds__(256) void k_cmfma(
    const u16* __restrict__ inp, const u16* __restrict__ wt,
    const float* __restrict__ bias, const float* __restrict__ mask,
    u16* __restrict__ out) {
  constexpr int HW = H * W;
  __shared__ __align__(16) u16 ldsA[128 * 64];
  __shared__ __align__(16) u16 ldsB[64 * 64];
  const int tid = threadIdx.x;
  const int wave = tid >> 6, lane = tid & 63;
  const int m0 = blockIdx.x * 128;
  const int n0 = blockIdx.y * 64;
  const int ss = (lane & 7) ^ (lane >> 3);
  const u16* aptr[4];
#pragma unroll
  for (int q = 0; q < 4; q++) {
    int m = m0 + wave * 32 + q * 8 + (lane >> 3);
    int b = m / HW, rem = m % HW;
    int yy = rem / W, xx = rem % W;
    aptr[q] = inp +
              ((size_t)((b * (H + 2) + yy + 1) * (W + 2)) + xx + 1) * CIN +
              ss * 8;
  }
  const u16* bptr[2];
#pragma unroll
  for (int q = 0; q < 2; q++) {
    int rb = wave * 16 + q * 8 + (lane >> 3);
    bptr[q] = wt + (size_t)(n0 + rb) * CIN + ss * 8;
  }
  u16* lA = ldsA + wave * 32 * 64;
  u16* lB = ldsB + wave * 16 * 64;
  const int arow0 = wave * 32 + (lane & 15);
  const int nrow = lane & 15;
  const int t0 = lane >> 4, x7 = lane & 7;
  f32x4 acc[2][4] = {};

#pragma unroll 1
  for (int tap = 0; tap < 9; tap++) {
    const int aoff = (tap / 3 - 1) * ((W + 2) * CIN) + (tap % 3 - 1) * CIN;
    const size_t woff = (size_t)tap * COUT * CIN;
#pragma unroll 1
    for (int c0 = 0; c0 < CIN; c0 += 64) {
      __syncthreads();
#pragma unroll
      for (int q = 0; q < 4; q++) gload16(aptr[q] + aoff + c0, lA + q * 512);
#pragma unroll
      for (int q = 0; q < 2; q++) gload16(bptr[q] + woff + c0, lB + q * 512);
      __syncthreads();
#pragma unroll
      for (int h = 0; h < 2; h++) {
        const int sl = (((h << 2) + t0) ^ x7) * 8;
        f16x8 af[2], bf[4];
#pragma unroll
        for (int i = 0; i < 2; i++)
          af[i] = *(const f16x8*)&ldsA[(arow0 + i * 16) * 64 + sl];
#pragma unroll
        for (int j = 0; j < 4; j++)
          bf[j] = *(const f16x8*)&ldsB[(nrow + j * 16) * 64 + sl];
#pragma unroll
        for (int i = 0; i < 2; i++)
#pragma unroll
          for (int j = 0; j < 4; j++)
            acc[i][j] = __builtin_amdgcn_mfma_f32_16x16x32_f16(
                af[i], bf[j], acc[i][j], 0, 0, 0);
      }
    }
  }
  float bn[4], mk[4];
#pragma unroll
  for (int j = 0; j < 4; j++) {
    int n = n0 + j * 16 + nrow;
    bn[j] = bias[n];
    mk[j] = MASKED ? mask[n] : 1.f;
  }
#pragma unroll
  for (int i = 0; i < 2; i++)
#pragma unroll
    for (int r = 0; r < 4; r++) {
      int m = m0 + wave * 32 + i * 16 + (lane >> 4) * 4 + r;
#pragma unroll
      for (int j = 0; j < 4; j++) {
        float v = acc[i][j][r] + bn[j];
        if (MASKED) v *= mk[j];
        out[(size_t)m * COUT + n0 + j * 16 + nrow] = f2h(v);
      }
    }
}

// ---------- split-K MFMA FC: p[ks][256][512] = A(256,K) @ W(512,K)^T ------
// A,W f16 row-major; partials f32, no bias (BN1d cancels constant shifts).
template <int K, int KSPLIT>
__global__ __launch_bounds__(256) void k_fcmfma(const u16* __restrict__ a,
                                                const u16* __restrict__ w,
                                                float* __restrict__ p) {
  constexpr int KCH = K / KSPLIT;
  __shared__ __align__(16) u16 ldsA[128 * 64];
  __shared__ __align__(16) u16 ldsB[64 * 64];
  const int tid = threadIdx.x;
  const int wave = tid >> 6, lane = tid & 63;
  const int m0 = blockIdx.x * 128;
  const int n0 = blockIdx.y * 64;
  const int ks = blockIdx.z;
  const int ss = (lane & 7) ^ (lane >> 3);
  const u16* aptr[4];
#pragma unroll
  for (int q = 0; q < 4; q++)
    aptr[q] =
        a + (size_t)(m0 + wave * 32 + q * 8 + (lane >> 3)) * K + ss * 8;
  const u16* bptr[2];
#pragma unroll
  for (int q = 0; q < 2; q++)
    bptr[q] =
        w + (size_t)(n0 + wave * 16 + q * 8 + (lane >> 3)) * K + ss * 8;
  u16* lA = ldsA + wave * 32 * 64;
  u16* lB = ldsB + wave * 16 * 64;
  const int arow0 = wave * 32 + (lane & 15);
  const int nrow = lane & 15;
  const int t0 = lane >> 4, x7 = lane & 7;
  f32x4 acc[2][4] = {};

#pragma unroll 1
  for (int kc = ks * KCH; kc < ks * KCH + KCH; kc += 64) {
    __syncthreads();
#pragma unroll
    for (int q = 0; q < 4; q++) gload16(aptr[q] + kc, lA + q * 512);
#pragma unroll
    for (int q = 0; q < 2; q++) gload16(bptr[q] + kc, lB + q * 512);
    __syncthreads();
#pragma unroll
    for (int h = 0; h < 2; h++) {
      const int sl = (((h << 2) + t0) ^ x7) * 8;
      f16x8 af[2], bf[4];
#pragma unroll
      for (int i = 0; i < 2; i++)
        af[i] = *(const f16x8*)&ldsA[(arow0 + i * 16) * 64 + sl];
#pragma unroll
      for (int j = 0; j < 4; j++)
        bf[j] = *(const f16x8*)&ldsB[(nrow + j * 16) * 64 + sl];
#pragma unroll
      for (int i = 0; i < 2; i++)
#pragma unroll
        for (int j = 0; j < 4; j++)
          acc[i][j] = __builtin_amdgcn_mfma_f32_16x16x32_f16(
              af[i], bf[j], acc[i][j], 0, 0, 0);
    }
  }
  float* po = p + (size_t)ks * (256 * 512);
#pragma unroll
  for (int i = 0; i < 2; i++)
#pragma unroll
    for (int r = 0; r < 4; r++) {
      int m = m0 + wave * 32 + i * 16 + (lane >> 4) * 4 + r;
#pragma unroll
      for (int j = 0; j < 4; j++)
        po[(size_t)m * 512 + n0 + j * 16 + nrow] = acc[i][j][r];
    }
}

// ---------- fused partial-sum + BN1d + relu -> f16 [256][512] ----------
// one wave per column; lane t holds rows {t, t+64, t+128, t+192} in-register
template <int NS>
__global__ __launch_bounds__(256) void k_bn1dfuse(const float* __restrict__ p,
                                                  const float* __restrict__ g,
                                                  const float* __restrict__ be,
                                                  u16* __restrict__ outp) {
  int wave = threadIdx.x >> 6, lane = threadIdx.x & 63;
  int c = blockIdx.x * 4 + wave;  // grid 128
  float v[4] = {};
#pragma unroll 1
  for (int s = 0; s < NS; s++) {
    const float* ps = p + (size_t)s * (256 * 512);
#pragma unroll
    for (int r = 0; r < 4; r++) v[r] += ps[(size_t)(lane + r * 64) * 512 + c];
  }
  float s1 = v[0] + v[1] + v[2] + v[3];
  float s2 = v[0] * v[0] + v[1] * v[1] + v[2] * v[2] + v[3] * v[3];
#pragma unroll
  for (int off = 32; off > 0; off >>= 1) {
    s1 += __shfl_xor(s1, off);
    s2 += __shfl_xor(s2, off);
  }
  float mu = s1 * (1.f / 256.f);
  float var = s2 * (1.f / 256.f) - mu * mu;
  float sc = g[c] * rsqrtf(var + 1e-5f);
  float sh = be[c] - mu * sc;
#pragma unroll
  for (int r = 0; r < 4; r++) {
    float y = fmaxf(v[r] * sc + sh, 0.f);
    outp[(size_t)(lane + r * 64) * 512 + c] = f2h(y);
  }
}

// ---------- per-channel sum/sumsq over f16 NHWC buffer ----------
template <int C>
__global__ __launch_bounds__(256) void k_bnstat(const u16* __restrict__ y,
                                                size_t T,
                                                float* __restrict__ stats) {
  constexpr int CH8 = C / 8;
  int tid = threadIdx.x;
  float s[8] = {}, ss[8] = {};
  for (size_t i = (size_t)blockIdx.x * 256 + tid; i < T;
       i += (size_t)gridDim.x * 256) {
    uint4 v = ((const uint4*)y)[i];
    u32 pv[4] = {v.x, v.y, v.z, v.w};
#pragma unroll
    for (int k = 0; k < 4; k++) {
      float lo = h2f((u16)(pv[k] & 0xffffu));
      float hi = h2f((u16)(pv[k] >> 16));
      s[2 * k] += lo;
      ss[2 * k] += lo * lo;
      s[2 * k + 1] += hi;
      ss[2 * k + 1] += hi * hi;
    }
  }
#pragma unroll
  for (int off = CH8; off < 64; off <<= 1) {
#pragma unroll
    for (int j = 0; j < 8; j++) {
      s[j] += __shfl_down(s[j], off);
      ss[j] += __shfl_down(ss[j], off);
    }
  }
  __shared__ float red[4][CH8][16];
  int wave = tid >> 6, lane = tid & 63;
  if (lane < CH8) {
#pragma unroll
    for (int j = 0; j < 8; j++) {
      red[wave][lane][j] = s[j];
      red[wave][lane][8 + j] = ss[j];
    }
  }
  __syncthreads();
  if (tid < CH8) {
#pragma unroll
    for (int j = 0; j < 8; j++) {
      float a = 0.f, b = 0.f;
#pragma unroll
      for (int w = 0; w < 4; w++) {
        a += red[w][tid][j];
        b += red[w][tid][8 + j];
      }
      int c = tid * 8 + j;
      atomicAdd(&stats[c * 2], a);
      atomicAdd(&stats[c * 2 + 1], b);
    }
  }
}

// ---------- BN affine + relu, write zero-padded f16 buffer ----------
template <int C, int H, int W>
__global__ __launch_bounds__(256) void k_bnrelu_pad(
    const u16* __restrict__ y, float invN, const float* __restrict__ st,
    const float* __restrict__ g, const float* __restrict__ be,
    u16* __restrict__ outp) {
  constexpr int CH8 = C / 8, HP = H + 2, WP = W + 2;
  __shared__ float sA[C], sB[C];
  int tid = threadIdx.x;
  if (tid < C) {
    float mu = st[tid * 2] * invN;
    float var = st[tid * 2 + 1] * invN - mu * mu;
    float sc = g[tid] * rsqrtf(var + 1e-5f);
    sA[tid] = sc;
    sB[tid] = be[tid] - mu * sc;
  }
  __syncthreads();
  const size_t T = (size_t)256 * HP * WP * CH8;
  for (size_t i = (size_t)blockIdx.x * 256 + tid; i < T;
       i += (size_t)gridDim.x * 256) {
    int slot = (int)(i % CH8);
    size_t t = i / CH8;
    int xx = (int)(t % WP);
    t /= WP;
    int yy = (int)(t % HP);
    int b = (int)(t / HP);
    uint4 o;
    if (yy == 0 || yy == HP - 1 || xx == 0 || xx == WP - 1) {
      o = make_uint4(0u, 0u, 0u, 0u);
    } else {
      uint4 v =
          ((const uint4*)y)[(((size_t)(b * H + yy - 1) * W) + xx - 1) * CH8 +
                            slot];
      u32 pv[4] = {v.x, v.y, v.z, v.w};
      u32 po[4];
      int c0 = slot * 8;
#pragma unroll
      for (int k = 0; k < 4; k++) {
        int c = c0 + 2 * k;
        float lo = fmaxf(h2f((u16)(pv[k] & 0xffffu)) * sA[c] + sB[c], 0.f);
        float hi =
            fmaxf(h2f((u16)(pv[k] >> 16)) * sA[c + 1] + sB[c + 1], 0.f);
        po[k] = (u32)f2h(lo) | ((u32)f2h(hi) << 16);
      }
      o = make_uint4(po[0], po[1], po[2], po[3]);
    }
    ((uint4*)outp)[i] = o;
  }
}

// ---------- BN affine + relu + 2x2 maxpool ----------
// NCHW=false: zero-padded f16 (HO+2, WO+2). NCHW=true: f16 NCHW flat.
template <int C, int H, int W, bool NCHW>
__global__ __launch_bounds__(256) void k_bnpool(
    const u16* __restrict__ y, float invN, const float* __restrict__ st,
    const float* __restrict__ g, const float* __restrict__ be,
    void* __restrict__ outv) {
  constexpr int CH8 = C / 8, HO = H / 2, WO = W / 2;
  constexpr int HP = NCHW ? HO : HO + 2, WP = NCHW ? WO : WO + 2;
  __shared__ float sA[C], sB[C];
  int tid = threadIdx.x;
  if (tid < C) {
    float mu = st[tid * 2] * invN;
    float var = st[tid * 2 + 1] * invN - mu * mu;
    float sc = g[tid] * rsqrtf(var + 1e-5f);
    sA[tid] = sc;
    sB[tid] = be[tid] - mu * sc;
  }
  __syncthreads();
  const size_t T = (size_t)256 * HP * WP * CH8;
  for (size_t i = (size_t)blockIdx.x * 256 + tid; i < T;
       i += (size_t)gridDim.x * 256) {
    int slot = (int)(i % CH8);
    size_t t = i / CH8;
    int xx = (int)(t % WP);
    t /= WP;
    int yy = (int)(t % HP);
    int b = (int)(t / HP);
    int px, py;
    bool border = false;
    if (NCHW) {
      px = xx;
      py = yy;
    } else {
      px = xx - 1;
      py = yy - 1;
      border = (yy == 0 || yy == HP - 1 || xx == 0 || xx == WP - 1);
    }
    if (border) {
      ((uint4*)outv)[i] = make_uint4(0u, 0u, 0u, 0u);
      continue;
    }
    const uint4* yp = (const uint4*)y;
    size_t i00 = (((size_t)(b * H + 2 * py) * W) + 2 * px) * CH8 + slot;
    uint4 v00 = yp[i00], v01 = yp[i00 + CH8];
    uint4 v10 = yp[i00 + (size_t)W * CH8], v11 = yp[i00 + (size_t)W * CH8 + CH8];
    u32 p00[4] = {v00.x, v00.y, v00.z, v00.w};
    u32 p01[4] = {v01.x, v01.y, v01.z, v01.w};
    u32 p10[4] = {v10.x, v10.y, v10.z, v10.w};
    u32 p11[4] = {v11.x, v11.y, v11.z, v11.w};
    int c0 = slot * 8;
    float r[8];
#pragma unroll
    for (int k = 0; k < 4; k++) {
      int c = c0 + 2 * k;
      float a_ = sA[c], b_ = sB[c], a2 = sA[c + 1], b2 = sB[c + 1];
      float l0 = fmaxf(h2f((u16)(p00[k] & 0xffffu)) * a_ + b_, 0.f);
      float l1 = fmaxf(h2f((u16)(p01[k] & 0xffffu)) * a_ + b_, 0.f);
      float l2 = fmaxf(h2f((u16)(p10[k] & 0xffffu)) * a_ + b_, 0.f);
      float l3 = fmaxf(h2f((u16)(p11[k] & 0xffffu)) * a_ + b_, 0.f);
      float h0 = fmaxf(h2f((u16)(p00[k] >> 16)) * a2 + b2, 0.f);
      float h1 = fmaxf(h2f((u16)(p01[k] >> 16)) * a2 + b2, 0.f);
      float h2 = fmaxf(h2f((u16)(p10[k] >> 16)) * a2 + b2, 0.f);
      float h3 = fmaxf(h2f((u16)(p11[k] >> 16)) * a2 + b2, 0.f);
      r[2 * k] = fmaxf(fmaxf(l0, l1), fmaxf(l2, l3));
      r[2 * k + 1] = fmaxf(fmaxf(h0, h1), fmaxf(h2, h3));
    }
    if (NCHW) {
      u16* of = (u16*)outv;
#pragma unroll
      for (int j = 0; j < 8; j++)
        of[((size_t)(b * C + c0 + j) * HO + py) * WO + px] = f2h(r[j]);
    } else {
      u32 po[4];
#pragma unroll
      for (int k = 0; k < 4; k++)
        po[k] = (u32)f2h(r[2 * k]) | ((u32)f2h(r[2 * k + 1]) << 16);
      ((uint4*)outv)[i] = make_uint4(po[0], po[1], po[2], po[3]);
    }
  }
}

// ---------- fc9: (256,512) f16 @ (10,512)^T f32 + b ----------
__global__ __launch_bounds__(256) void k_fc9(const u16* __restrict__ a,
                                             const float* __restrict__ w,
                                             const float* __restrict__ bias,
                                             float* __restrict__ out) {
  int b = blockIdx.x, tid = threadIdx.x;
  int o = tid & 15, ch = tid >> 4;
  float s = 0.f;
  if (o < 10) {
    const u16* ap = a + (size_t)b * 512 + ch * 32;
    const float* wp = w + (size_t)o * 512 + ch * 32;
#pragma unroll
    for (int k = 0; k < 32; k++) s += h2f(ap[k]) * wp[k];
  }
  __shared__ float red[16][17];
  red[ch][o] = s;
  __syncthreads();
  if (tid < 10) {
    float t = bias[tid];
#pragma unroll
    for (int c2 = 0; c2 < 16; c2++) t += red[c2][tid];
    out[b * 10 + tid] = t;
  }
}

// ---------- ALSH: per-filter sumsq + hash dots ----------
__global__ __launch_bounds__(256) void k_w6stats(const float* __restrict__ w6,
                                                 const float* __restrict__ ha,
                                                 float* __restrict__ wstats) {
  int f = blockIdx.x, tid = threadIdx.x;
  const float* wp = w6 + (size_t)f * 2304;
  float ss = 0.f, d0 = 0.f, d1 = 0.f;
#pragma unroll
  for (int k = 0; k < 9; k++) {
    float v = wp[k * 256 + tid];
    ss += v * v;
    d0 += v * ha[k * 256 + tid];
    d1 += v * ha[2306 + k * 256 + tid];
  }
  for (int off = 32; off > 0; off >>= 1) {
    ss += __shfl_down(ss, off);
    d0 += __shfl_down(d0, off);
    d1 += __shfl_down(d1, off);
  }
  __shared__ float r[4][3];
  int wv = tid >> 6, ln = tid & 63;
  if (ln == 0) {
    r[wv][0] = ss;
    r[wv][1] = d0;
    r[wv][2] = d1;
  }
  __syncthreads();
  if (tid == 0) {
    float a0 = 0.f, a1 = 0.f, a2 = 0.f;
    for (int i = 0; i < 4; i++) {
      a0 += r[i][0];
      a1 += r[i][1];
      a2 += r[i][2];
    }
    wstats[f * 4 + 0] = a0;
    wstats[f * 4 + 1] = a1;
    wstats[f * 4 + 2] = a2;
  }
}

// ---------- ALSH: final mask ----------
__global__ __launch_bounds__(256) void k_mask(const float* __restrict__ wstats,
                                              const float* __restrict__ qstats,
                                              const float* __restrict__ ha,
                                              float invN,
                                              float* __restrict__ mask) {
  int tid = threadIdx.x;
  __shared__ float red[256];
  float n2 = wstats[tid * 4];
  red[tid] = n2;
  __syncthreads();
  for (int off = 128; off > 0; off >>= 1) {
    if (tid < off) red[tid] = fmaxf(red[tid], red[tid + off]);
    __syncthreads();
  }
  float maxn2 = red[0];
  float qm = qstats[tid * 2] * invN;
  float h0 = 0.f, h1 = 0.f;
#pragma unroll
  for (int k = 0; k < 9; k++) {
    h0 += ha[k * 256 + tid];
    h1 += ha[2306 + k * 256 + tid];
  }
  __shared__ float r0[256], r1[256];
  r0[tid] = qm * h0;
  r1[tid] = qm * h1;
  __syncthreads();
  for (int off = 128; off > 0; off >>= 1) {
    if (tid < off) {
      r0[tid] += r0[tid + off];
      r1[tid] += r1[tid + off];
    }
    __syncthreads();
  }
  float qd0 = r0[0], qd1 = r1[0];
  float s = U_CONST / sqrtf(maxn2);
  float ns2 = s * s * wstats[tid * 4];
  float v0 = s * wstats[tid * 4 + 1] + ns2 * ha[2304] + ns2 * ns2 * ha[2305];
  float v1 = s * wstats[tid * 4 + 2] + ns2 * ha[2306 + 2304] +
             ns2 * ns2 * ha[2306 + 2305];
  bool bf0 = v0 > 0.f, bf1 = v1 > 0.f;
  bool bq0 = qd0 > 0.f, bq1 = qd1 > 0.f;
  mask[tid] = (bf0 == bq0 && bf1 == bq1) ? 1.f : 0.f;
}

// ======================================================================
extern "C" void kernel_launch(void* const* d_in, const int* in_sizes, int n_in,
                              void* d_out, int out_size, void* d_ws,
                              size_t ws_size, hipStream_t stream) {
  (void)in_sizes; (void)n_in; (void)out_size; (void)ws_size;
  const float* x = (const float*)d_in[0];
  const float* w1 = (const float*)d_in[1];
  const float* b1 = (const float*)d_in[2];
  const float* g1 = (const float*)d_in[3];
  const float* be1 = (const float*)d_in[4];
  const float* w2 = (const float*)d_in[5];
  const float* g2 = (const float*)d_in[7];
  const float* be2 = (const float*)d_in[8];
  const float* w3 = (const float*)d_in[9];
  const float* g3 = (const float*)d_in[11];
  const float* be3 = (const float*)d_in[12];
  const float* w4 = (const float*)d_in[13];
  const float* g4 = (const float*)d_in[15];
  const float* be4 = (const float*)d_in[16];
  const float* w5 = (const float*)d_in[17];
  const float* g5 = (const float*)d_in[19];
  const float* be5 = (const float*)d_in[20];
  const float* w6 = (const float*)d_in[21];
  const float* g6 = (const float*)d_in[23];
  const float* be6 = (const float*)d_in[24];
  const float* hash_a = (const float*)d_in[25];
  const float* fc7_w = (const float*)d_in[26];
  const float* g7 = (const float*)d_in[28];
  const float* be7 = (const float*)d_in[29];
  const float* fc8_w = (const float*)d_in[30];
  const float* g8 = (const float*)d_in[32];
  const float* be8 = (const float*)d_in[33];
  const float* fc9_w = (const float*)d_in[34];
  const float* fc9_b = (const float*)d_in[35];
  // conv biases b2..b6 are exact no-ops under BN (constant per channel,
  // removed by mean subtraction) and are zeros in setup; b2..b6 pointers
  // still passed to k_cmfma for generality:
  const float* b2 = (const float*)d_in[6];
  const float* b3 = (const float*)d_in[10];
  const float* b4 = (const float*)d_in[14];
  const float* b5 = (const float*)d_in[18];
  const float* b6 = (const float*)d_in[22];

  char* wsb = (char*)d_ws;
  float* stats = (float*)(wsb + OFFB_STATS);
  float* wstats = (float*)(wsb + OFFB_WSTAT);
  float* maskb = (float*)(wsb + OFFB_MASK);
  u16* fcin = (u16*)(wsb + OFFB_FCIN);
  u16* w7t = (u16*)(wsb + OFFB_W7T);
  u16* w8t = (u16*)(wsb + OFFB_W8T);
  float* p7 = (float*)(wsb + OFFB_P7);
  float* p8 = (float*)(wsb + OFFB_P8);
  u16* a7 = (u16*)(wsb + OFFB_A7);
  u16* a8 = (u16*)(wsb + OFFB_A8);
  u16* wt2 = (u16*)(wsb + OFFB_WT2);
  u16* wt3 = (u16*)(wsb + OFFB_WT3);
  u16* wt4 = (u16*)(wsb + OFFB_WT4);
  u16* wt5 = (u16*)(wsb + OFFB_WT5);
  u16* wt6 = (u16*)(wsb + OFFB_WT6);
  u16* slab1 = (u16*)(wsb + OFFB_SLAB1);
  u16* slab2 = (u16*)(wsb + OFFB_SLAB2);
  float* xt = (float*)(wsb + OFFB_SLAB2);
  float* outp = (float*)d_out;

  hipMemsetAsync(stats, 0, 3584 * sizeof(float), stream);

  k_xform_x<<<3072, 256, 0, stream>>>(x, xt);
  k_xform_w<<<144, 256, 0, stream>>>(w2, wt2, 64, 64);
  k_xform_w<<<288, 256, 0, stream>>>(w3, wt3, 128, 64);
  k_xform_w<<<576, 256, 0, stream>>>(w4, wt4, 128, 128);
  k_xform_w<<<1152, 256, 0, stream>>>(w5, wt5, 256, 128);
  k_xform_w<<<2304, 256, 0, stream>>>(w6, wt6, 256, 256);
  k_cvt_h<<<2048, 256, 0, stream>>>(fc7_w, w7t, 512 * 4096);
  k_cvt_h<<<256, 256, 0, stream>>>(fc8_w, w8t, 512 * 512);
  k_w6stats<<<256, 256, 0, stream>>>(w6, hash_a, wstats);

  // layer 1: conv(3->64)@32x32 (fp32 math, f16 out)
  k_conv1<<<4096, 256, 0, stream>>>(xt, w1, b1, slab1);
  k_bnstat<64><<<512, 256, 0, stream>>>(slab1, (size_t)2097152, stats + 0);
  k_bnrelu_pad<64, 32, 32><<<1024, 256, 0, stream>>>(
      slab1, 1.f / 262144.f, stats + 0, g1, be1, slab2);
  // layer 2
  k_cmfma<64, 64, 32, 32, false><<<dim3(2048, 1), 256, 0, stream>>>(
      slab2, wt2, b2, nullptr, slab1);
  k_bnstat<64><<<512, 256, 0, stream>>>(slab1, (size_t)2097152, stats + 512);
  k_bnpool<64, 32, 32, false><<<512, 256, 0, stream>>>(
      slab1, 1.f / 262144.f, stats + 512, g2, be2, slab2);
  // layer 3
  k_cmfma<64, 128, 16, 16, false><<<dim3(512, 2), 256, 0, stream>>>(
      slab2, wt3, b3, nullptr, slab1);
  k_bnstat<128><<<512, 256, 0, stream>>>(slab1, (size_t)1048576, stats + 1024);
  k_bnrelu_pad<128, 16, 16><<<1024, 256, 0, stream>>>(
      slab1, 1.f / 65536.f, stats + 1024, g3, be3, slab2);
  // layer 4
  k_cmfma<128, 128, 16, 16, false><<<dim3(512, 2), 256, 0, stream>>>(
      slab2, wt4, b4, nullptr, slab1);
  k_bnstat<128><<<512, 256, 0, stream>>>(slab1, (size_t)1048576, stats + 1536);
  k_bnpool<128, 16, 16, false><<<512, 256, 0, stream>>>(
      slab1, 1.f / 65536.f, stats + 1536, g4, be4, slab2);
  // layer 5
  k_cmfma<128, 256, 8, 8, false><<<dim3(128, 4), 256, 0, stream>>>(
      slab2, wt5, b5, nullptr, slab1);
  k_bnstat<256><<<512, 256, 0, stream>>>(slab1, (size_t)524288, stats + 2048);
  k_bnrelu_pad<256, 8, 8><<<1024, 256, 0, stream>>>(
      slab1, 1.f / 16384.f, stats + 2048, g5, be5, slab2);
  // ALSH mask
  k_bnstat<256><<<512, 256, 0, stream>>>(slab2, (size_t)819200, stats + 3072);
  k_mask<<<1, 256, 0, stream>>>(wstats, stats + 3072, hash_a, 1.f / 16384.f,
                                maskb);
  // layer 6 (masked), pool -> f16 NCHW flat (fcin)
  k_cmfma<256, 256, 8, 8, true><<<dim3(128, 4), 256, 0, stream>>>(
      slab2, wt6, b6, maskb, slab1);
  k_bnstat<256><<<512, 256, 0, stream>>>(slab1, (size_t)524288, stats + 2560);
  k_bnpool<256, 8, 8, true><<<512, 256, 0, stream>>>(
      slab1, 1.f / 16384.f, stats + 2560, g6, be6, fcin);
  // FC head: split-K MFMA + fused BN1d
  k_fcmfma<4096, 16><<<dim3(2, 8, 16), 256, 0, stream>>>(fcin, w7t, p7);
  k_bn1dfuse<16><<<128, 256, 0, stream>>>(p7, g7, be7, a7);
  k_fcmfma<512, 8><<<dim3(2, 8, 8), 256, 0, stream>>>(a7, w8t, p8);
  k_bn1dfuse<8><<<128, 256, 0, stream>>>(p8, g8, be8, a8);
  k_fc9<<<256, 256, 0, stream>>>(a8, fc9_w, fc9_b, outp);
}

// Round 8
// 427.318 us; speedup vs baseline: 4.7590x; 4.2078x over previous
//
#include <hip/hip_runtime.h>

typedef unsigned short u16;
typedef unsigned int u32;
typedef __attribute__((ext_vector_type(8))) _Float16 f16x8;
typedef __attribute__((ext_vector_type(4))) float f32x4;

#define U_CONST 0.999f

// ---------- byte offsets in d_ws ----------
constexpr size_t OFFB_STATS = 0;          // 3584 f32 (7 layers x 512)
constexpr size_t OFFB_WSTAT = 14336;      // 256*4 f32
constexpr size_t OFFB_MASK  = 18432;      // 256 f32
constexpr size_t OFFB_FCIN  = 32768;      // f16 [256][4096] = 2MB
constexpr size_t OFFB_W7T   = 2129920;    // f16 [512][4096] = 4MB
constexpr size_t OFFB_W8T   = 6324224;    // f16 [512][512]
constexpr size_t OFFB_P7    = 6848512;    // f32 [16][256][512] = 8MB (FC phase)
constexpr size_t OFFB_P8    = 15237120;   // f32 [8][256][512]  = 4MB (FC phase)
constexpr size_t OFFB_A7    = 19431424;   // f16 [256][512]
constexpr size_t OFFB_A8    = 19693568;   // f16 [256][512]
constexpr size_t OFFB_WT2   = 20971520;   // f16 conv weights [tap][co][ci]
constexpr size_t OFFB_WT3   = 21045248;
constexpr size_t OFFB_WT4   = 21192704;
constexpr size_t OFFB_WT5   = 21487616;
constexpr size_t OFFB_WT6   = 22077440;
constexpr size_t OFFB_SLAB1 = 25165824;   // conv outputs (<=33.6MB)
constexpr size_t OFFB_SLAB2 = 60817408;   // xt + padded activations (<=38MB)
// partial-stat slabs reuse FC-phase scratch (dead during conv layers):
constexpr size_t OFFB_PART  = OFFB_P7;    // <=2MB  (2 planes x C x gridX f32)
constexpr size_t OFFB_QPART = OFFB_P8;    // 1MB    (256 x 1024 f32)

// ---------- helpers ----------
__device__ __forceinline__ u16 f2h(float f) {
  _Float16 h = (_Float16)f;
  return __builtin_bit_cast(u16, h);
}
__device__ __forceinline__ float h2f(u16 u) {
  return (float)__builtin_bit_cast(_Float16, u);
}
__device__ __forceinline__ void gload16(const void* g, void* l) {
  __builtin_amdgcn_global_load_lds(
      (const __attribute__((address_space(1))) unsigned int*)g,
      (__attribute__((address_space(3))) unsigned int*)l, 16, 0, 0);
}

// ---------- layout transforms ----------
__global__ __launch_bounds__(256) void k_xform_x(const float* __restrict__ x,
                                                 float* __restrict__ xt) {
  int idx = blockIdx.x * 256 + threadIdx.x;
  if (idx >= 256 * 3 * 1024) return;
  int c = idx % 3;
  int t = idx / 3;
  int s = t % 1024;
  int b = t / 1024;
  xt[idx] = x[(b * 3 + c) * 1024 + s];
}

__global__ __launch_bounds__(256) void k_xform_w(const float* __restrict__ w,
                                                 u16* __restrict__ wt, int CO,
                                                 int CI) {
  int total = CO * CI * 9;
  for (int idx = blockIdx.x * 256 + threadIdx.x; idx < total;
       idx += gridDim.x * 256) {
    int ci = idx % CI;
    int t = idx / CI;
    int co = t % CO;
    int tap = t / CO;
    wt[idx] = f2h(w[(co * CI + ci) * 9 + tap]);
  }
}

__global__ __launch_bounds__(256) void k_cvt_h(const float* __restrict__ w,
                                               u16* __restrict__ o, int n) {
  for (int i = blockIdx.x * 256 + threadIdx.x; i < n; i += gridDim.x * 256)
    o[i] = f2h(w[i]);
}

// ---------- conv1 (CIN=3), fp32 math, f16 out, fused stat partials --------
__global__ __launch_bounds__(256) void k_conv1(const float* __restrict__ xt,
                                               const float* __restrict__ w1,
                                               const float* __restrict__ b1,
                                               u16* __restrict__ y,
                                               float* __restrict__ part) {
  __shared__ float Ins[4 * 34 * 3];
  __shared__ float Ws[27 * 64];
  __shared__ float sred[64 * 16 * 2];
  int tid = threadIdx.x;
  int m0 = blockIdx.x * 64;
  int b = m0 >> 10;
  int y0 = (m0 & 1023) >> 5;

  for (int i = tid; i < 27 * 64; i += 256) {
    int co = i & 63;
    int t = i >> 6;
    int ci = t % 3;
    int tap = t / 3;
    Ws[i] = w1[co * 27 + ci * 9 + tap];
  }
  for (int i = tid; i < 4 * 34 * 3; i += 256) {
    int ci = i % 3;
    int t = i / 3;
    int xx = t % 34;
    int yy = t / 34;
    int gy = y0 - 1 + yy;
    int gx = xx - 1;
    float v = 0.f;
    if ((unsigned)gy < 32u && (unsigned)gx < 32u)
      v = xt[((b * 32 + gy) * 32 + gx) * 3 + ci];
    Ins[i] = v;
  }
  __syncthreads();

  int tr = tid >> 4, tc = tid & 15;
  float acc[4][4] = {};
#pragma unroll
  for (int tap = 0; tap < 9; tap++) {
    int dy = tap / 3, dx = tap % 3;
#pragma unroll
    for (int ci = 0; ci < 3; ci++) {
      float4 wv = *(const float4*)&Ws[(tap * 3 + ci) * 64 + tc * 4];
#pragma unroll
      for (int i = 0; i < 4; i++) {
        int r = tr * 4 + i;
        int yy = (r >> 5) + dy;
        int xx = (r & 31) + dx;
        float a = Ins[(yy * 34 + xx) * 3 + ci];
        acc[i][0] += a * wv.x;
        acc[i][1] += a * wv.y;
        acc[i][2] += a * wv.z;
        acc[i][3] += a * wv.w;
      }
    }
  }
  float4 bb = *(const float4*)&b1[tc * 4];
  float cs[4] = {}, cq[4] = {};
#pragma unroll
  for (int i = 0; i < 4; i++) {
    size_t r = (size_t)(m0 + tr * 4 + i);
    float v0 = acc[i][0] + bb.x, v1 = acc[i][1] + bb.y;
    float v2 = acc[i][2] + bb.z, v3 = acc[i][3] + bb.w;
    cs[0] += v0; cq[0] += v0 * v0;
    cs[1] += v1; cq[1] += v1 * v1;
    cs[2] += v2; cq[2] += v2 * v2;
    cs[3] += v3; cq[3] += v3 * v3;
    u32 lo = (u32)f2h(v0) | ((u32)f2h(v1) << 16);
    u32 hi = (u32)f2h(v2) | ((u32)f2h(v3) << 16);
    *(uint2*)&y[r * 64 + tc * 4] = make_uint2(lo, hi);
  }
#pragma unroll
  for (int q = 0; q < 4; q++) {
    sred[((tc * 4 + q) * 16 + tr) * 2] = cs[q];
    sred[((tc * 4 + q) * 16 + tr) * 2 + 1] = cq[q];
  }
  __syncthreads();
  if (tid < 64) {
    float s = 0.f, q = 0.f;
#pragma unroll
    for (int t = 0; t < 16; t++) {
      s += sred[(tid * 16 + t) * 2];
      q += sred[(tid * 16 + t) * 2 + 1];
    }
    part[(size_t)tid * gridDim.x + blockIdx.x] = s;
    part[(size_t)(64 + tid) * gridDim.x + blockIdx.x] = q;
  }
}

// ---------- f16 MFMA implicit-GEMM 3x3 conv, fused stat partials ----------
template <int CIN, int COUT, int H, int W, bool MASKED>
__global__ __launch_bounds__(256) void k_cmfma(
    const u16* __restrict__ inp, const u16* __restrict__ wt,
    const float* __restrict__ bias, const float* __restrict__ mask,
    u16* __restrict__ out, float* __restrict__ part) {
  constexpr int HW = H * W;
  __shared__ __align__(16) u16 ldsA[128 * 64];
  __shared__ __align__(16) u16 ldsB[64 * 64];
  const int tid = threadIdx.x;
  const int wave = tid >> 6, lane = tid & 63;
  const int m0 = blockIdx.x * 128;
  const int n0 = blockIdx.y * 64;
  const int ss = (lane & 7) ^ (lane >> 3);
  const u16* aptr[4];
#pragma unroll
  for (int q = 0; q < 4; q++) {
    int m = m0 + wave * 32 + q * 8 + (lane >> 3);
    int b = m / HW, rem = m % HW;
    int yy = rem / W, xx = rem % W;
    aptr[q] = inp +
              ((size_t)((b * (H + 2) + yy + 1) * (W + 2)) + xx + 1) * CIN +
              ss * 8;
  }
  const u16* bptr[2];
#pragma unroll
  for (int q = 0; q < 2; q++) {
    int rb = wave * 16 + q * 8 + (lane >> 3);
    bptr[q] = wt + (size_t)(n0 + rb) * CIN + ss * 8;
  }
  u16* lA = ldsA + wave * 32 * 64;
  u16* lB = ldsB + wave * 16 * 64;
  const int arow0 = wave * 32 + (lane & 15);
  const int nrow = lane & 15;
  const int t0 = lane >> 4, x7 = lane & 7;
  f32x4 acc[2][4] = {};

#pragma unroll 1
  for (int tap = 0; tap < 9; tap++) {
    const int aoff = (tap / 3 - 1) * ((W + 2) * CIN) + (tap % 3 - 1) * CIN;
    const size_t woff = (size_t)tap * COUT * CIN;
#pragma unroll 1
    for (int c0 = 0; c0 < CIN; c0 += 64) {
      __syncthreads();
#pragma unroll
      for (int q = 0; q < 4; q++) gload16(aptr[q] + aoff + c0, lA + q * 512);
#pragma unroll
      for (int q = 0; q < 2; q++) gload16(bptr[q] + woff + c0, lB + q * 512);
      __syncthreads();
#pragma unroll
      for (int h = 0; h < 2; h++) {
        const int sl = (((h << 2) + t0) ^ x7) * 8;
        f16x8 af[2], bf[4];
#pragma unroll
        for (int i = 0; i < 2; i++)
          af[i] = *(const f16x8*)&ldsA[(arow0 + i * 16) * 64 + sl];
#pragma unroll
        for (int j = 0; j < 4; j++)
          bf[j] = *(const f16x8*)&ldsB[(nrow + j * 16) * 64 + sl];
#pragma unroll
        for (int i = 0; i < 2; i++)
#pragma unroll
          for (int j = 0; j < 4; j++)
            acc[i][j] = __builtin_amdgcn_mfma_f32_16x16x32_f16(
                af[i], bf[j], acc[i][j], 0, 0, 0);
      }
    }
  }
  float bn[4], mk[4];
#pragma unroll
  for (int j = 0; j < 4; j++) {
    int n = n0 + j * 16 + nrow;
    bn[j] = bias[n];
    mk[j] = MASKED ? mask[n] : 1.f;
  }
  float ps[4] = {}, pq[4] = {};
#pragma unroll
  for (int i = 0; i < 2; i++)
#pragma unroll
    for (int r = 0; r < 4; r++) {
      int m = m0 + wave * 32 + i * 16 + (lane >> 4) * 4 + r;
#pragma unroll
      for (int j = 0; j < 4; j++) {
        float v = acc[i][j][r] + bn[j];
        if (MASKED) v *= mk[j];
        out[(size_t)m * COUT + n0 + j * 16 + nrow] = f2h(v);
        ps[j] += v;
        pq[j] += v * v;
      }
    }
  // channel c = n0 + j*16 + nrow lives in lanes {nrow, nrow+16, +32, +48}
#pragma unroll
  for (int j = 0; j < 4; j++) {
    ps[j] += __shfl_xor(ps[j], 16);
    pq[j] += __shfl_xor(pq[j], 16);
    ps[j] += __shfl_xor(ps[j], 32);
    pq[j] += __shfl_xor(pq[j], 32);
  }
  __syncthreads();  // all waves past their last LDS read -> reuse ldsA
  float* red = (float*)ldsA;  // [4][64][2]
  if (lane < 16) {
#pragma unroll
    for (int j = 0; j < 4; j++) {
      red[(wave * 64 + j * 16 + lane) * 2] = ps[j];
      red[(wave * 64 + j * 16 + lane) * 2 + 1] = pq[j];
    }
  }
  __syncthreads();
  if (tid < 64) {
    float s = 0.f, q = 0.f;
#pragma unroll
    for (int w = 0; w < 4; w++) {
      s += red[(w * 64 + tid) * 2];
      q += red[(w * 64 + tid) * 2 + 1];
    }
    part[(size_t)(n0 + tid) * gridDim.x + blockIdx.x] = s;
    part[(size_t)(COUT + n0 + tid) * gridDim.x + blockIdx.x] = q;
  }
}

// ---------- reduce per-block partials -> stats[c*2], stats[c*2+1] ----------
__global__ __launch_bounds__(256) void k_redstat(const float* __restrict__ part,
                                                 float* __restrict__ stats,
                                                 int NB, int C) {
  int c = blockIdx.x;
  const float* ps = part + (size_t)c * NB;
  const float* pq = part + (size_t)(C + c) * NB;
  int tid = threadIdx.x;
  float s = 0.f, q = 0.f;
  for (int t = tid; t < NB; t += 256) {
    s += ps[t];
    q += pq[t];
  }
#pragma unroll
  for (int off = 32; off > 0; off >>= 1) {
    s += __shfl_xor(s, off);
    q += __shfl_xor(q, off);
  }
  __shared__ float r2[4][2];
  int wave = tid >> 6, lane = tid & 63;
  if (lane == 0) {
    r2[wave][0] = s;
    r2[wave][1] = q;
  }
  __syncthreads();
  if (tid == 0) {
    stats[c * 2] = r2[0][0] + r2[1][0] + r2[2][0] + r2[3][0];
    stats[c * 2 + 1] = r2[0][1] + r2[1][1] + r2[2][1] + r2[3][1];
  }
}

// ---------- reduce q partials (sum only) -> qstat[c] ----------
__global__ __launch_bounds__(256) void k_qred(const float* __restrict__ qpart,
                                              float* __restrict__ qstat,
                                              int NB) {
  int c = blockIdx.x;
  const float* ps = qpart + (size_t)c * NB;
  int tid = threadIdx.x;
  float s = 0.f;
  for (int t = tid; t < NB; t += 256) s += ps[t];
#pragma unroll
  for (int off = 32; off > 0; off >>= 1) s += __shfl_xor(s, off);
  __shared__ float r2[4];
  int wave = tid >> 6, lane = tid & 63;
  if (lane == 0) r2[wave] = s;
  __syncthreads();
  if (tid == 0) qstat[c] = r2[0] + r2[1] + r2[2] + r2[3];
}

// ---------- BN affine + relu, write zero-padded f16 (opt. q-sum fusion) ----
template <int C, int H, int W, bool QSUM>
__global__ __launch_bounds__(256) void k_bnrelu_pad(
    const u16* __restrict__ y, float invN, const float* __restrict__ st,
    const float* __restrict__ g, const float* __restrict__ be,
    u16* __restrict__ outp, float* __restrict__ qpart) {
  constexpr int CH8 = C / 8, HP = H + 2, WP = W + 2;
  __shared__ float sA[C], sB[C];
  __shared__ float qred[QSUM ? 4 : 1][32][8];
  int tid = threadIdx.x;
  if (tid < C) {
    float mu = st[tid * 2] * invN;
    float var = st[tid * 2 + 1] * invN - mu * mu;
    float sc = g[tid] * rsqrtf(var + 1e-5f);
    sA[tid] = sc;
    sB[tid] = be[tid] - mu * sc;
  }
  __syncthreads();
  float qs[8] = {};
  const size_t T = (size_t)256 * HP * WP * CH8;
  for (size_t i = (size_t)blockIdx.x * 256 + tid; i < T;
       i += (size_t)gridDim.x * 256) {
    int slot = (int)(i % CH8);
    size_t t = i / CH8;
    int xx = (int)(t % WP);
    t /= WP;
    int yy = (int)(t % HP);
    int b = (int)(t / HP);
    uint4 o;
    if (yy == 0 || yy == HP - 1 || xx == 0 || xx == WP - 1) {
      o = make_uint4(0u, 0u, 0u, 0u);
    } else {
      uint4 v =
          ((const uint4*)y)[(((size_t)(b * H + yy - 1) * W) + xx - 1) * CH8 +
                            slot];
      u32 pv[4] = {v.x, v.y, v.z, v.w};
      u32 po[4];
      int c0 = slot * 8;
#pragma unroll
      for (int k = 0; k < 4; k++) {
        int c = c0 + 2 * k;
        float lo = fmaxf(h2f((u16)(pv[k] & 0xffffu)) * sA[c] + sB[c], 0.f);
        float hi =
            fmaxf(h2f((u16)(pv[k] >> 16)) * sA[c + 1] + sB[c + 1], 0.f);
        if (QSUM) {
          qs[2 * k] += lo;
          qs[2 * k + 1] += hi;
        }
        po[k] = (u32)f2h(lo) | ((u32)f2h(hi) << 16);
      }
      o = make_uint4(po[0], po[1], po[2], po[3]);
    }
    ((uint4*)outp)[i] = o;
  }
  if (QSUM) {
    // slot is constant per thread: stride (gridDim.x*256) % CH8 == 0,
    // so thread's channels are (tid&31)*8 + {0..7}
    int wave = tid >> 6, lane = tid & 63;
#pragma unroll
    for (int j = 0; j < 8; j++) qs[j] += __shfl_xor(qs[j], 32);
    if (lane < 32) {
#pragma unroll
      for (int j = 0; j < 8; j++) qred[wave][lane][j] = qs[j];
    }
    __syncthreads();
    int slot = tid >> 3, jj = tid & 7;
    float s = qred[0][slot][jj] + qred[1][slot][jj] + qred[2][slot][jj] +
              qred[3][slot][jj];
    qpart[(size_t)(slot * 8 + jj) * gridDim.x + blockIdx.x] = s;
  }
}

// ---------- BN affine + relu + 2x2 maxpool ----------
template <int C, int H, int W, bool NCHW>
__global__ __launch_bounds__(256) void k_bnpool(
    const u16* __restrict__ y, float invN, const float* __restrict__ st,
    const float* __restrict__ g, const float* __restrict__ be,
    void* __restrict__ outv) {
  constexpr int CH8 = C / 8, HO = H / 2, WO = W / 2;
  constexpr int HP = NCHW ? HO : HO + 2, WP = NCHW ? WO : WO + 2;
  __shared__ float sA[C], sB[C];
  int tid = threadIdx.x;
  if (tid < C) {
    float mu = st[tid * 2] * invN;
    float var = st[tid * 2 + 1] * invN - mu * mu;
    float sc = g[tid] * rsqrtf(var + 1e-5f);
    sA[tid] = sc;
    sB[tid] = be[tid] - mu * sc;
  }
  __syncthreads();
  const size_t T = (size_t)256 * HP * WP * CH8;
  for (size_t i = (size_t)blockIdx.x * 256 + tid; i < T;
       i += (size_t)gridDim.x * 256) {
    int slot = (int)(i % CH8);
    size_t t = i / CH8;
    int xx = (int)(t % WP);
    t /= WP;
    int yy = (int)(t % HP);
    int b = (int)(t / HP);
    int px, py;
    bool border = false;
    if (NCHW) {
      px = xx;
      py = yy;
    } else {
      px = xx - 1;
      py = yy - 1;
      border = (yy == 0 || yy == HP - 1 || xx == 0 || xx == WP - 1);
    }
    if (border) {
      ((uint4*)outv)[i] = make_uint4(0u, 0u, 0u, 0u);
      continue;
    }
    const uint4* yp = (const uint4*)y;
    size_t i00 = (((size_t)(b * H + 2 * py) * W) + 2 * px) * CH8 + slot;
    uint4 v00 = yp[i00], v01 = yp[i00 + CH8];
    uint4 v10 = yp[i00 + (size_t)W * CH8], v11 = yp[i00 + (size_t)W * CH8 + CH8];
    u32 p00[4] = {v00.x, v00.y, v00.z, v00.w};
    u32 p01[4] = {v01.x, v01.y, v01.z, v01.w};
    u32 p10[4] = {v10.x, v10.y, v10.z, v10.w};
    u32 p11[4] = {v11.x, v11.y, v11.z, v11.w};
    int c0 = slot * 8;
    float r[8];
#pragma unroll
    for (int k = 0; k < 4; k++) {
      int c = c0 + 2 * k;
      float a_ = sA[c], b_ = sB[c], a2 = sA[c + 1], b2 = sB[c + 1];
      float l0 = fmaxf(h2f((u16)(p00[k] & 0xffffu)) * a_ + b_, 0.f);
      float l1 = fmaxf(h2f((u16)(p01[k] & 0xffffu)) * a_ + b_, 0.f);
      float l2 = fmaxf(h2f((u16)(p10[k] & 0xffffu)) * a_ + b_, 0.f);
      float l3 = fmaxf(h2f((u16)(p11[k] & 0xffffu)) * a_ + b_, 0.f);
      float h0 = fmaxf(h2f((u16)(p00[k] >> 16)) * a2 + b2, 0.f);
      float h1 = fmaxf(h2f((u16)(p01[k] >> 16)) * a2 + b2, 0.f);
      float h2 = fmaxf(h2f((u16)(p10[k] >> 16)) * a2 + b2, 0.f);
      float h3 = fmaxf(h2f((u16)(p11[k] >> 16)) * a2 + b2, 0.f);
      r[2 * k] = fmaxf(fmaxf(l0, l1), fmaxf(l2, l3));
      r[2 * k + 1] = fmaxf(fmaxf(h0, h1), fmaxf(h2, h3));
    }
    if (NCHW) {
      u16* of = (u16*)outv;
#pragma unroll
      for (int j = 0; j < 8; j++)
        of[((size_t)(b * C + c0 + j) * HO + py) * WO + px] = f2h(r[j]);
    } else {
      u32 po[4];
#pragma unroll
      for (int k = 0; k < 4; k++)
        po[k] = (u32)f2h(r[2 * k]) | ((u32)f2h(r[2 * k + 1]) << 16);
      ((uint4*)outv)[i] = make_uint4(po[0], po[1], po[2], po[3]);
    }
  }
}

// ---------- split-K MFMA FC ----------
template <int K, int KSPLIT>
__global__ __launch_bounds__(256) void k_fcmfma(const u16* __restrict__ a,
                                                const u16* __restrict__ w,
                                                float* __restrict__ p) {
  constexpr int KCH = K / KSPLIT;
  __shared__ __align__(16) u16 ldsA[128 * 64];
  __shared__ __align__(16) u16 ldsB[64 * 64];
  const int tid = threadIdx.x;
  const int wave = tid >> 6, lane = tid & 63;
  const int m0 = blockIdx.x * 128;
  const int n0 = blockIdx.y * 64;
  const int ks = blockIdx.z;
  const int ss = (lane & 7) ^ (lane >> 3);
  const u16* aptr[4];
#pragma unroll
  for (int q = 0; q < 4; q++)
    aptr[q] = a + (size_t)(m0 + wave * 32 + q * 8 + (lane >> 3)) * K + ss * 8;
  const u16* bptr[2];
#pragma unroll
  for (int q = 0; q < 2; q++)
    bptr[q] = w + (size_t)(n0 + wave * 16 + q * 8 + (lane >> 3)) * K + ss * 8;
  u16* lA = ldsA + wave * 32 * 64;
  u16* lB = ldsB + wave * 16 * 64;
  const int arow0 = wave * 32 + (lane & 15);
  const int nrow = lane & 15;
  const int t0 = lane >> 4, x7 = lane & 7;
  f32x4 acc[2][4] = {};

#pragma unroll 1
  for (int kc = ks * KCH; kc < ks * KCH + KCH; kc += 64) {
    __syncthreads();
#pragma unroll
    for (int q = 0; q < 4; q++) gload16(aptr[q] + kc, lA + q * 512);
#pragma unroll
    for (int q = 0; q < 2; q++) gload16(bptr[q] + kc, lB + q * 512);
    __syncthreads();
#pragma unroll
    for (int h = 0; h < 2; h++) {
      const int sl = (((h << 2) + t0) ^ x7) * 8;
      f16x8 af[2], bf[4];
#pragma unroll
      for (int i = 0; i < 2; i++)
        af[i] = *(const f16x8*)&ldsA[(arow0 + i * 16) * 64 + sl];
#pragma unroll
      for (int j = 0; j < 4; j++)
        bf[j] = *(const f16x8*)&ldsB[(nrow + j * 16) * 64 + sl];
#pragma unroll
      for (int i = 0; i < 2; i++)
#pragma unroll
        for (int j = 0; j < 4; j++)
          acc[i][j] = __builtin_amdgcn_mfma_f32_16x16x32_f16(
              af[i], bf[j], acc[i][j], 0, 0, 0);
    }
  }
  float* po = p + (size_t)ks * (256 * 512);
#pragma unroll
  for (int i = 0; i < 2; i++)
#pragma unroll
    for (int r = 0; r < 4; r++) {
      int m = m0 + wave * 32 + i * 16 + (lane >> 4) * 4 + r;
#pragma unroll
      for (int j = 0; j < 4; j++)
        po[(size_t)m * 512 + n0 + j * 16 + nrow] = acc[i][j][r];
    }
}

// ---------- fused partial-sum + BN1d + relu -> f16 [256][512] ----------
template <int NS>
__global__ __launch_bounds__(256) void k_bn1dfuse(const float* __restrict__ p,
                                                  const float* __restrict__ g,
                                                  const float* __restrict__ be,
                                                  u16* __restrict__ outp) {
  int wave = threadIdx.x >> 6, lane = threadIdx.x & 63;
  int c = blockIdx.x * 4 + wave;
  float v[4] = {};
#pragma unroll 1
  for (int s = 0; s < NS; s++) {
    const float* ps = p + (size_t)s * (256 * 512);
#pragma unroll
    for (int r = 0; r < 4; r++) v[r] += ps[(size_t)(lane + r * 64) * 512 + c];
  }
  float s1 = v[0] + v[1] + v[2] + v[3];
  float s2 = v[0] * v[0] + v[1] * v[1] + v[2] * v[2] + v[3] * v[3];
#pragma unroll
  for (int off = 32; off > 0; off >>= 1) {
    s1 += __shfl_xor(s1, off);
    s2 += __shfl_xor(s2, off);
  }
  float mu = s1 * (1.f / 256.f);
  float var = s2 * (1.f / 256.f) - mu * mu;
  float sc = g[c] * rsqrtf(var + 1e-5f);
  float sh = be[c] - mu * sc;
#pragma unroll
  for (int r = 0; r < 4; r++) {
    float y = fmaxf(v[r] * sc + sh, 0.f);
    outp[(size_t)(lane + r * 64) * 512 + c] = f2h(y);
  }
}

// ---------- fc9 ----------
__global__ __launch_bounds__(256) void k_fc9(const u16* __restrict__ a,
                                             const float* __restrict__ w,
                                             const float* __restrict__ bias,
                                             float* __restrict__ out) {
  int b = blockIdx.x, tid = threadIdx.x;
  int o = tid & 15, ch = tid >> 4;
  float s = 0.f;
  if (o < 10) {
    const u16* ap = a + (size_t)b * 512 + ch * 32;
    const float* wp = w + (size_t)o * 512 + ch * 32;
#pragma unroll
    for (int k = 0; k < 32; k++) s += h2f(ap[k]) * wp[k];
  }
  __shared__ float red[16][17];
  red[ch][o] = s;
  __syncthreads();
  if (tid < 10) {
    float t = bias[tid];
#pragma unroll
    for (int c2 = 0; c2 < 16; c2++) t += red[c2][tid];
    out[b * 10 + tid] = t;
  }
}

// ---------- ALSH: per-filter sumsq + hash dots ----------
__global__ __launch_bounds__(256) void k_w6stats(const float* __restrict__ w6,
                                                 const float* __restrict__ ha,
                                                 float* __restrict__ wstats) {
  int f = blockIdx.x, tid = threadIdx.x;
  const float* wp = w6 + (size_t)f * 2304;
  float ss = 0.f, d0 = 0.f, d1 = 0.f;
#pragma unroll
  for (int k = 0; k < 9; k++) {
    float v = wp[k * 256 + tid];
    ss += v * v;
    d0 += v * ha[k * 256 + tid];
    d1 += v * ha[2306 + k * 256 + tid];
  }
  for (int off = 32; off > 0; off >>= 1) {
    ss += __shfl_down(ss, off);
    d0 += __shfl_down(d0, off);
    d1 += __shfl_down(d1, off);
  }
  __shared__ float r[4][3];
  int wv = tid >> 6, ln = tid & 63;
  if (ln == 0) {
    r[wv][0] = ss;
    r[wv][1] = d0;
    r[wv][2] = d1;
  }
  __syncthreads();
  if (tid == 0) {
    float a0 = 0.f, a1 = 0.f, a2 = 0.f;
    for (int i = 0; i < 4; i++) {
      a0 += r[i][0];
      a1 += r[i][1];
      a2 += r[i][2];
    }
    wstats[f * 4 + 0] = a0;
    wstats[f * 4 + 1] = a1;
    wstats[f * 4 + 2] = a2;
  }
}

// ---------- ALSH: final mask ----------
__global__ __launch_bounds__(256) void k_mask(const float* __restrict__ wstats,
                                              const float* __restrict__ qstats,
                                              const float* __restrict__ ha,
                                              float invN,
                                              float* __restrict__ mask) {
  int tid = threadIdx.x;
  __shared__ float red[256];
  float n2 = wstats[tid * 4];
  red[tid] = n2;
  __syncthreads();
  for (int off = 128; off > 0; off >>= 1) {
    if (tid < off) red[tid] = fmaxf(red[tid], red[tid + off]);
    __syncthreads();
  }
  float maxn2 = red[0];
  float qm = qstats[tid] * invN;
  float h0 = 0.f, h1 = 0.f;
#pragma unroll
  for (int k = 0; k < 9; k++) {
    h0 += ha[k * 256 + tid];
    h1 += ha[2306 + k * 256 + tid];
  }
  __shared__ float r0[256], r1[256];
  r0[tid] = qm * h0;
  r1[tid] = qm * h1;
  __syncthreads();
  for (int off = 128; off > 0; off >>= 1) {
    if (tid < off) {
      r0[tid] += r0[tid + off];
      r1[tid] += r1[tid + off];
    }
    __syncthreads();
  }
  float qd0 = r0[0], qd1 = r1[0];
  float s = U_CONST / sqrtf(maxn2);
  float ns2 = s * s * wstats[tid * 4];
  float v0 = s * wstats[tid * 4 + 1] + ns2 * ha[2304] + ns2 * ns2 * ha[2305];
  float v1 = s * wstats[tid * 4 + 2] + ns2 * ha[2306 + 2304] +
             ns2 * ns2 * ha[2306 + 2305];
  bool bf0 = v0 > 0.f, bf1 = v1 > 0.f;
  bool bq0 = qd0 > 0.f, bq1 = qd1 > 0.f;
  mask[tid] = (bf0 == bq0 && bf1 == bq1) ? 1.f : 0.f;
}

// ======================================================================
extern "C" void kernel_launch(void* const* d_in, const int* in_sizes, int n_in,
                              void* d_out, int out_size, void* d_ws,
                              size_t ws_size, hipStream_t stream) {
  (void)in_sizes; (void)n_in; (void)out_size; (void)ws_size;
  const float* x = (const float*)d_in[0];
  const float* w1 = (const float*)d_in[1];
  const float* b1 = (const float*)d_in[2];
  const float* g1 = (const float*)d_in[3];
  const float* be1 = (const float*)d_in[4];
  const float* w2 = (const float*)d_in[5];
  const float* b2 = (const float*)d_in[6];
  const float* g2 = (const float*)d_in[7];
  const float* be2 = (const float*)d_in[8];
  const float* w3 = (const float*)d_in[9];
  const float* b3 = (const float*)d_in[10];
  const float* g3 = (const float*)d_in[11];
  const float* be3 = (const float*)d_in[12];
  const float* w4 = (const float*)d_in[13];
  const float* b4 = (const float*)d_in[14];
  const float* g4 = (const float*)d_in[15];
  const float* be4 = (const float*)d_in[16];
  const float* w5 = (const float*)d_in[17];
  const float* b5 = (const float*)d_in[18];
  const float* g5 = (const float*)d_in[19];
  const float* be5 = (const float*)d_in[20];
  const float* w6 = (const float*)d_in[21];
  const float* b6 = (const float*)d_in[22];
  const float* g6 = (const float*)d_in[23];
  const float* be6 = (const float*)d_in[24];
  const float* hash_a = (const float*)d_in[25];
  const float* fc7_w = (const float*)d_in[26];
  const float* g7 = (const float*)d_in[28];
  const float* be7 = (const float*)d_in[29];
  const float* fc8_w = (const float*)d_in[30];
  const float* g8 = (const float*)d_in[32];
  const float* be8 = (const float*)d_in[33];
  const float* fc9_w = (const float*)d_in[34];
  const float* fc9_b = (const float*)d_in[35];

  char* wsb = (char*)d_ws;
  float* stats = (float*)(wsb + OFFB_STATS);
  float* wstats = (float*)(wsb + OFFB_WSTAT);
  float* maskb = (float*)(wsb + OFFB_MASK);
  u16* fcin = (u16*)(wsb + OFFB_FCIN);
  u16* w7t = (u16*)(wsb + OFFB_W7T);
  u16* w8t = (u16*)(wsb + OFFB_W8T);
  float* p7 = (float*)(wsb + OFFB_P7);
  float* p8 = (float*)(wsb + OFFB_P8);
  u16* a7 = (u16*)(wsb + OFFB_A7);
  u16* a8 = (u16*)(wsb + OFFB_A8);
  float* part = (float*)(wsb + OFFB_PART);
  float* qpart = (float*)(wsb + OFFB_QPART);
  u16* wt2 = (u16*)(wsb + OFFB_WT2);
  u16* wt3 = (u16*)(wsb + OFFB_WT3);
  u16* wt4 = (u16*)(wsb + OFFB_WT4);
  u16* wt5 = (u16*)(wsb + OFFB_WT5);
  u16* wt6 = (u16*)(wsb + OFFB_WT6);
  u16* slab1 = (u16*)(wsb + OFFB_SLAB1);
  u16* slab2 = (u16*)(wsb + OFFB_SLAB2);
  float* xt = (float*)(wsb + OFFB_SLAB2);
  float* outp = (float*)d_out;

  k_xform_x<<<3072, 256, 0, stream>>>(x, xt);
  k_xform_w<<<144, 256, 0, stream>>>(w2, wt2, 64, 64);
  k_xform_w<<<288, 256, 0, stream>>>(w3, wt3, 128, 64);
  k_xform_w<<<576, 256, 0, stream>>>(w4, wt4, 128, 128);
  k_xform_w<<<1152, 256, 0, stream>>>(w5, wt5, 256, 128);
  k_xform_w<<<2304, 256, 0, stream>>>(w6, wt6, 256, 256);
  k_cvt_h<<<2048, 256, 0, stream>>>(fc7_w, w7t, 512 * 4096);
  k_cvt_h<<<256, 256, 0, stream>>>(fc8_w, w8t, 512 * 512);
  k_w6stats<<<256, 256, 0, stream>>>(w6, hash_a, wstats);

  // layer 1
  k_conv1<<<4096, 256, 0, stream>>>(xt, w1, b1, slab1, part);
  k_redstat<<<64, 256, 0, stream>>>(part, stats + 0, 4096, 64);
  k_bnrelu_pad<64, 32, 32, false><<<1024, 256, 0, stream>>>(
      slab1, 1.f / 262144.f, stats + 0, g1, be1, slab2, nullptr);
  // layer 2
  k_cmfma<64, 64, 32, 32, false><<<dim3(2048, 1), 256, 0, stream>>>(
      slab2, wt2, b2, nullptr, slab1, part);
  k_redstat<<<64, 256, 0, stream>>>(part, stats + 512, 2048, 64);
  k_bnpool<64, 32, 32, false><<<512, 256, 0, stream>>>(
      slab1, 1.f / 262144.f, stats + 512, g2, be2, slab2);
  // layer 3
  k_cmfma<64, 128, 16, 16, false><<<dim3(512, 2), 256, 0, stream>>>(
      slab2, wt3, b3, nullptr, slab1, part);
  k_redstat<<<128, 256, 0, stream>>>(part, stats + 1024, 512, 128);
  k_bnrelu_pad<128, 16, 16, false><<<1024, 256, 0, stream>>>(
      slab1, 1.f / 65536.f, stats + 1024, g3, be3, slab2, nullptr);
  // layer 4
  k_cmfma<128, 128, 16, 16, false><<<dim3(512, 2), 256, 0, stream>>>(
      slab2, wt4, b4, nullptr, slab1, part);
  k_redstat<<<128, 256, 0, stream>>>(part, stats + 1536, 512, 128);
  k_bnpool<128, 16, 16, false><<<512, 256, 0, stream>>>(
      slab1, 1.f / 65536.f, stats + 1536, g4, be4, slab2);
  // layer 5
  k_cmfma<128, 256, 8, 8, false><<<dim3(128, 4), 256, 0, stream>>>(
      slab2, wt5, b5, nullptr, slab1, part);
  k_redstat<<<256, 256, 0, stream>>>(part, stats + 2048, 128, 256);
  k_bnrelu_pad<256, 8, 8, true><<<1024, 256, 0, stream>>>(
      slab1, 1.f / 16384.f, stats + 2048, g5, be5, slab2, qpart);
  // ALSH mask
  k_qred<<<256, 256, 0, stream>>>(qpart, stats + 3072, 1024);
  k_mask<<<1, 256, 0, stream>>>(wstats, stats + 3072, hash_a, 1.f / 16384.f,
                                maskb);
  // layer 6 (masked)
  k_cmfma<256, 256, 8, 8, true><<<dim3(128, 4), 256, 0, stream>>>(
      slab2, wt6, b6, maskb, slab1, part);
  k_redstat<<<256, 256, 0, stream>>>(part, stats + 2560, 128, 256);
  k_bnpool<256, 8, 8, true><<<512, 256, 0, stream>>>(
      slab1, 1.f / 16384.f, stats + 2560, g6, be6, fcin);
  // FC head
  k_fcmfma<4096, 16><<<dim3(2, 8, 16), 256, 0, stream>>>(fcin, w7t, p7);
  k_bn1dfuse<16><<<128, 256, 0, stream>>>(p7, g7, be7, a7);
  k_fcmfma<512, 8><<<dim3(2, 8, 8), 256, 0, stream>>>(a7, w8t, p8);
  k_bn1dfuse<8><<<128, 256, 0, stream>>>(p8, g8, be8, a8);
  k_fc9<<<256, 256, 0, stream>>>(a8, fc9_w, fc9_b, outp);
}

// Round 10
// 424.055 us; speedup vs baseline: 4.7956x; 1.0077x over previous
//
#include <hip/hip_runtime.h>

typedef unsigned short u16;
typedef unsigned int u32;
typedef __attribute__((ext_vector_type(8))) _Float16 f16x8;
typedef __attribute__((ext_vector_type(4))) float f32x4;

#define U_CONST 0.999f

// ---------- byte offsets in d_ws ----------
constexpr size_t OFFB_STATS = 0;          // 3584 f32 (7 layers x 512)
constexpr size_t OFFB_WSTAT = 14336;      // 256*4 f32
constexpr size_t OFFB_MASK  = 18432;      // 256 f32
constexpr size_t OFFB_FCIN  = 32768;      // f16 [256][4096] = 2MB
constexpr size_t OFFB_W7T   = 2129920;    // f16 [512][4096] = 4MB
constexpr size_t OFFB_W8T   = 6324224;    // f16 [512][512]
constexpr size_t OFFB_P7    = 6848512;    // f32 [16][256][512] = 8MB (FC phase)
constexpr size_t OFFB_P8    = 15237120;   // f32 [8][256][512]  = 4MB (FC phase)
constexpr size_t OFFB_A7    = 19431424;   // f16 [256][512]
constexpr size_t OFFB_A8    = 19693568;   // f16 [256][512]
constexpr size_t OFFB_WT2   = 20971520;   // f16 conv weights [tap][co][ci]
constexpr size_t OFFB_WT3   = 21045248;
constexpr size_t OFFB_WT4   = 21192704;
constexpr size_t OFFB_WT5   = 21487616;
constexpr size_t OFFB_WT6   = 22077440;
constexpr size_t OFFB_SLAB1 = 25165824;   // conv outputs (<=33.6MB)
constexpr size_t OFFB_SLAB2 = 60817408;   // padded activations (<=38MB)
// partial-stat slabs reuse FC-phase scratch (dead during conv layers):
constexpr size_t OFFB_PART  = OFFB_P7;    // <=2MB
constexpr size_t OFFB_QPART = OFFB_P8;    // 1MB

// ---------- helpers ----------
__device__ __forceinline__ u16 f2h(float f) {
  _Float16 h = (_Float16)f;
  return __builtin_bit_cast(u16, h);
}
__device__ __forceinline__ float h2f(u16 u) {
  return (float)__builtin_bit_cast(_Float16, u);
}
__device__ __forceinline__ void gload16(const void* g, void* l) {
  __builtin_amdgcn_global_load_lds(
      (const __attribute__((address_space(1))) unsigned int*)g,
      (__attribute__((address_space(3))) unsigned int*)l, 16, 0, 0);
}

// ---------- fused weight prep: 5 conv xforms + 2 fc converts ----------
__global__ __launch_bounds__(256) void k_wprep(
    const float* __restrict__ w2, const float* __restrict__ w3,
    const float* __restrict__ w4, const float* __restrict__ w5,
    const float* __restrict__ w6, const float* __restrict__ f7,
    const float* __restrict__ f8, u16* __restrict__ o2, u16* __restrict__ o3,
    u16* __restrict__ o4, u16* __restrict__ o5, u16* __restrict__ o6,
    u16* __restrict__ o7, u16* __restrict__ o8) {
  for (int i = blockIdx.x * 256 + threadIdx.x; i < 3502080;
       i += gridDim.x * 256) {
    if (i < 1142784) {
      const float* w;
      u16* o;
      int e, CO, CI;
      if (i < 36864) { w = w2; o = o2; e = i; CO = 64; CI = 64; }
      else if (i < 110592) { w = w3; o = o3; e = i - 36864; CO = 128; CI = 64; }
      else if (i < 258048) { w = w4; o = o4; e = i - 110592; CO = 128; CI = 128; }
      else if (i < 552960) { w = w5; o = o5; e = i - 258048; CO = 256; CI = 128; }
      else { w = w6; o = o6; e = i - 552960; CO = 256; CI = 256; }
      int ci = e % CI;
      int t = e / CI;
      int co = t % CO;
      int tap = t / CO;
      o[e] = f2h(w[(co * CI + ci) * 9 + tap]);
    } else if (i < 3239936) {
      int e = i - 1142784;
      o7[e] = f2h(f7[e]);
    } else {
      int e = i - 3239936;
      o8[e] = f2h(f8[e]);
    }
  }
}

// ---------- conv1 (CIN=3) reads NCHW x directly; fp32 math; f16 out -------
__global__ __launch_bounds__(256) void k_conv1(const float* __restrict__ x,
                                               const float* __restrict__ w1,
                                               const float* __restrict__ b1,
                                               u16* __restrict__ y,
                                               float* __restrict__ part) {
  __shared__ float Ins[3 * 4 * 34];   // [ci][yy][xx]
  __shared__ float Ws[27 * 64];
  __shared__ float sred[64 * 16 * 2];
  int tid = threadIdx.x;
  int m0 = blockIdx.x * 64;
  int b = m0 >> 10;
  int y0 = (m0 & 1023) >> 5;

  for (int i = tid; i < 27 * 64; i += 256) {
    int co = i & 63;
    int t = i >> 6;
    int ci = t % 3;
    int tap = t / 3;
    Ws[i] = w1[co * 27 + ci * 9 + tap];
  }
  for (int i = tid; i < 3 * 4 * 34; i += 256) {
    int xx = i % 34;
    int t = i / 34;
    int yy = t & 3;
    int ci = t >> 2;
    int gy = y0 - 1 + yy;
    int gx = xx - 1;
    float v = 0.f;
    if ((unsigned)gy < 32u && (unsigned)gx < 32u)
      v = x[((size_t)(b * 3 + ci) * 32 + gy) * 32 + gx];
    Ins[i] = v;
  }
  __syncthreads();

  int tr = tid >> 4, tc = tid & 15;
  float acc[4][4] = {};
#pragma unroll
  for (int tap = 0; tap < 9; tap++) {
    int dy = tap / 3, dx = tap % 3;
#pragma unroll
    for (int ci = 0; ci < 3; ci++) {
      float4 wv = *(const float4*)&Ws[(tap * 3 + ci) * 64 + tc * 4];
#pragma unroll
      for (int i = 0; i < 4; i++) {
        int r = tr * 4 + i;
        int yy = (r >> 5) + dy;
        int xx = (r & 31) + dx;
        float a = Ins[(ci * 4 + yy) * 34 + xx];
        acc[i][0] += a * wv.x;
        acc[i][1] += a * wv.y;
        acc[i][2] += a * wv.z;
        acc[i][3] += a * wv.w;
      }
    }
  }
  float4 bb = *(const float4*)&b1[tc * 4];
  float cs[4] = {}, cq[4] = {};
#pragma unroll
  for (int i = 0; i < 4; i++) {
    size_t r = (size_t)(m0 + tr * 4 + i);
    float v0 = acc[i][0] + bb.x, v1 = acc[i][1] + bb.y;
    float v2 = acc[i][2] + bb.z, v3 = acc[i][3] + bb.w;
    cs[0] += v0; cq[0] += v0 * v0;
    cs[1] += v1; cq[1] += v1 * v1;
    cs[2] += v2; cq[2] += v2 * v2;
    cs[3] += v3; cq[3] += v3 * v3;
    u32 lo = (u32)f2h(v0) | ((u32)f2h(v1) << 16);
    u32 hi = (u32)f2h(v2) | ((u32)f2h(v3) << 16);
    *(uint2*)&y[r * 64 + tc * 4] = make_uint2(lo, hi);
  }
#pragma unroll
  for (int q = 0; q < 4; q++) {
    sred[((tc * 4 + q) * 16 + tr) * 2] = cs[q];
    sred[((tc * 4 + q) * 16 + tr) * 2 + 1] = cq[q];
  }
  __syncthreads();
  if (tid < 64) {
    float s = 0.f, q = 0.f;
#pragma unroll
    for (int t = 0; t < 16; t++) {
      s += sred[(tid * 16 + t) * 2];
      q += sred[(tid * 16 + t) * 2 + 1];
    }
    part[(size_t)tid * gridDim.x + blockIdx.x] = s;
    part[(size_t)(64 + tid) * gridDim.x + blockIdx.x] = q;
  }
}

// ---------- f16 MFMA implicit-GEMM 3x3 conv, 64x64 wave tile --------------
// block = 4 waves arranged WM x WN; BM=WM*64, BN=WN*64; wave tile 64x64.
template <int CIN, int COUT, int H, int W, int WM, int WN, bool MASKED>
__global__ __launch_bounds__(256) void k_cmfma(
    const u16* __restrict__ inp, const u16* __restrict__ wt,
    const float* __restrict__ bias, const float* __restrict__ mask,
    u16* __restrict__ out, float* __restrict__ part) {
  constexpr int HW = H * W;
  constexpr int BM = WM * 64, BN = WN * 64;
  constexpr int RPW = BM / 4;        // A rows staged per wave
  constexpr int RBW = BN / 4;        // B rows staged per wave
  constexpr int ALD = RPW / 8;       // A gloads per thread
  constexpr int BLD = RBW / 8;       // B gloads per thread
  __shared__ __align__(16) u16 ldsA[BM * 64];
  __shared__ __align__(16) u16 ldsB[BN * 64];
  const int tid = threadIdx.x;
  const int wave = tid >> 6, lane = tid & 63;
  const int m0 = blockIdx.x * BM;
  const int n0 = blockIdx.y * BN;
  const int ss = (lane & 7) ^ (lane >> 3);
  const u16* aptr[ALD];
#pragma unroll
  for (int q = 0; q < ALD; q++) {
    int m = m0 + wave * RPW + q * 8 + (lane >> 3);
    int b = m / HW, rem = m % HW;
    int yy = rem / W, xx = rem % W;
    aptr[q] = inp +
              ((size_t)((b * (H + 2) + yy + 1) * (W + 2)) + xx + 1) * CIN +
              ss * 8;
  }
  const u16* bptr[BLD];
#pragma unroll
  for (int q = 0; q < BLD; q++) {
    int rb = n0 + wave * RBW + q * 8 + (lane >> 3);
    bptr[q] = wt + (size_t)rb * CIN + ss * 8;
  }
  u16* lA = ldsA + wave * RPW * 64;
  u16* lB = ldsB + wave * RBW * 64;
  const int wm = wave / WN, wn = wave % WN;
  const int fr = lane & 15;          // fragment row (A) / col (B)
  const int t0 = lane >> 4, x7 = lane & 7;
  f32x4 acc[4][4] = {};

#pragma unroll 1
  for (int tap = 0; tap < 9; tap++) {
    const int aoff = (tap / 3 - 1) * ((W + 2) * CIN) + (tap % 3 - 1) * CIN;
    const size_t woff = (size_t)tap * COUT * CIN;
#pragma unroll 1
    for (int c0 = 0; c0 < CIN; c0 += 64) {
      __syncthreads();
#pragma unroll
      for (int q = 0; q < ALD; q++) gload16(aptr[q] + aoff + c0, lA + q * 512);
#pragma unroll
      for (int q = 0; q < BLD; q++) gload16(bptr[q] + woff + c0, lB + q * 512);
      __syncthreads();
#pragma unroll
      for (int h = 0; h < 2; h++) {
        const int sl = (((h << 2) + t0) ^ x7) * 8;
        f16x8 af[4], bf[4];
#pragma unroll
        for (int i = 0; i < 4; i++)
          af[i] = *(const f16x8*)&ldsA[(wm * 64 + i * 16 + fr) * 64 + sl];
#pragma unroll
        for (int j = 0; j < 4; j++)
          bf[j] = *(const f16x8*)&ldsB[(wn * 64 + j * 16 + fr) * 64 + sl];
#pragma unroll
        for (int i = 0; i < 4; i++)
#pragma unroll
          for (int j = 0; j < 4; j++)
            acc[i][j] = __builtin_amdgcn_mfma_f32_16x16x32_f16(
                af[i], bf[j], acc[i][j], 0, 0, 0);
      }
    }
  }
  float bn[4], mk[4];
#pragma unroll
  for (int j = 0; j < 4; j++) {
    int n = n0 + wn * 64 + j * 16 + fr;
    bn[j] = bias[n];
    mk[j] = MASKED ? mask[n] : 1.f;
  }
  float ps[4] = {}, pq[4] = {};
#pragma unroll
  for (int i = 0; i < 4; i++)
#pragma unroll
    for (int r = 0; r < 4; r++) {
      int m = m0 + wm * 64 + i * 16 + t0 * 4 + r;
#pragma unroll
      for (int j = 0; j < 4; j++) {
        float v = acc[i][j][r] + bn[j];
        if (MASKED) v *= mk[j];
        out[(size_t)m * COUT + n0 + wn * 64 + j * 16 + fr] = f2h(v);
        ps[j] += v;
        pq[j] += v * v;
      }
    }
  // channel (wn*64 + j*16 + fr) partial lives in lanes {fr, fr+16, +32, +48}
#pragma unroll
  for (int j = 0; j < 4; j++) {
    ps[j] += __shfl_xor(ps[j], 16);
    pq[j] += __shfl_xor(pq[j], 16);
    ps[j] += __shfl_xor(ps[j], 32);
    pq[j] += __shfl_xor(pq[j], 32);
  }
  __syncthreads();  // all waves done with LDS tiles -> reuse ldsA
  float* red = (float*)ldsA;  // [4][64][2]
  if (lane < 16) {
#pragma unroll
    for (int j = 0; j < 4; j++) {
      red[(wave * 64 + j * 16 + lane) * 2] = ps[j];
      red[(wave * 64 + j * 16 + lane) * 2 + 1] = pq[j];
    }
  }
  __syncthreads();
  if (tid < 64 * WN) {
    int wn_t = tid >> 6, cc = tid & 63;
    float s = 0.f, q = 0.f;
#pragma unroll
    for (int w = 0; w < WM; w++) {
      s += red[((w * WN + wn_t) * 64 + cc) * 2];
      q += red[((w * WN + wn_t) * 64 + cc) * 2 + 1];
    }
    part[(size_t)(n0 + tid) * gridDim.x + blockIdx.x] = s;
    part[(size_t)(COUT + n0 + tid) * gridDim.x + blockIdx.x] = q;
  }
}

// ---------- reduce per-block partials -> stats ----------
__global__ __launch_bounds__(256) void k_redstat(const float* __restrict__ part,
                                                 float* __restrict__ stats,
                                                 int NB, int C) {
  int c = blockIdx.x;
  const float* ps = part + (size_t)c * NB;
  const float* pq = part + (size_t)(C + c) * NB;
  int tid = threadIdx.x;
  float s = 0.f, q = 0.f;
  for (int t = tid; t < NB; t += 256) {
    s += ps[t];
    q += pq[t];
  }
#pragma unroll
  for (int off = 32; off > 0; off >>= 1) {
    s += __shfl_xor(s, off);
    q += __shfl_xor(q, off);
  }
  __shared__ float r2[4][2];
  int wave = tid >> 6, lane = tid & 63;
  if (lane == 0) {
    r2[wave][0] = s;
    r2[wave][1] = q;
  }
  __syncthreads();
  if (tid == 0) {
    stats[c * 2] = r2[0][0] + r2[1][0] + r2[2][0] + r2[3][0];
    stats[c * 2 + 1] = r2[0][1] + r2[1][1] + r2[2][1] + r2[3][1];
  }
}

// ---------- reduce q partials (sum only) ----------
__global__ __launch_bounds__(256) void k_qred(const float* __restrict__ qpart,
                                              float* __restrict__ qstat,
                                              int NB) {
  int c = blockIdx.x;
  const float* ps = qpart + (size_t)c * NB;
  int tid = threadIdx.x;
  float s = 0.f;
  for (int t = tid; t < NB; t += 256) s += ps[t];
#pragma unroll
  for (int off = 32; off > 0; off >>= 1) s += __shfl_xor(s, off);
  __shared__ float r2[4];
  int wave = tid >> 6, lane = tid & 63;
  if (lane == 0) r2[wave] = s;
  __syncthreads();
  if (tid == 0) qstat[c] = r2[0] + r2[1] + r2[2] + r2[3];
}

// ---------- BN affine + relu, write zero-padded f16 (opt. q-sum fusion) ----
template <int C, int H, int W, bool QSUM>
__global__ __launch_bounds__(256) void k_bnrelu_pad(
    const u16* __restrict__ y, float invN, const float* __restrict__ st,
    const float* __restrict__ g, const float* __restrict__ be,
    u16* __restrict__ outp, float* __restrict__ qpart) {
  constexpr int CH8 = C / 8, HP = H + 2, WP = W + 2;
  __shared__ float sA[C], sB[C];
  __shared__ float qred[QSUM ? 4 : 1][32][8];
  int tid = threadIdx.x;
  if (tid < C) {
    float mu = st[tid * 2] * invN;
    float var = st[tid * 2 + 1] * invN - mu * mu;
    float sc = g[tid] * rsqrtf(var + 1e-5f);
    sA[tid] = sc;
    sB[tid] = be[tid] - mu * sc;
  }
  __syncthreads();
  float qs[8] = {};
  const size_t T = (size_t)256 * HP * WP * CH8;
  for (size_t i = (size_t)blockIdx.x * 256 + tid; i < T;
       i += (size_t)gridDim.x * 256) {
    int slot = (int)(i % CH8);
    size_t t = i / CH8;
    int xx = (int)(t % WP);
    t /= WP;
    int yy = (int)(t % HP);
    int b = (int)(t / HP);
    uint4 o;
    if (yy == 0 || yy == HP - 1 || xx == 0 || xx == WP - 1) {
      o = make_uint4(0u, 0u, 0u, 0u);
    } else {
      uint4 v =
          ((const uint4*)y)[(((size_t)(b * H + yy - 1) * W) + xx - 1) * CH8 +
                            slot];
      u32 pv[4] = {v.x, v.y, v.z, v.w};
      u32 po[4];
      int c0 = slot * 8;
#pragma unroll
      for (int k = 0; k < 4; k++) {
        int c = c0 + 2 * k;
        float lo = fmaxf(h2f((u16)(pv[k] & 0xffffu)) * sA[c] + sB[c], 0.f);
        float hi =
            fmaxf(h2f((u16)(pv[k] >> 16)) * sA[c + 1] + sB[c + 1], 0.f);
        if (QSUM) {
          qs[2 * k] += lo;
          qs[2 * k + 1] += hi;
        }
        po[k] = (u32)f2h(lo) | ((u32)f2h(hi) << 16);
      }
      o = make_uint4(po[0], po[1], po[2], po[3]);
    }
    ((uint4*)outp)[i] = o;
  }
  if (QSUM) {
    int wave = tid >> 6, lane = tid & 63;
#pragma unroll
    for (int j = 0; j < 8; j++) qs[j] += __shfl_xor(qs[j], 32);
    if (lane < 32) {
#pragma unroll
      for (int j = 0; j < 8; j++) qred[wave][lane][j] = qs[j];
    }
    __syncthreads();
    int slot = tid >> 3, jj = tid & 7;
    float s = qred[0][slot][jj] + qred[1][slot][jj] + qred[2][slot][jj] +
              qred[3][slot][jj];
    qpart[(size_t)(slot * 8 + jj) * gridDim.x + blockIdx.x] = s;
  }
}

// ---------- BN affine + relu + 2x2 maxpool ----------
template <int C, int H, int W, bool NCHW>
__global__ __launch_bounds__(256) void k_bnpool(
    const u16* __restrict__ y, float invN, const float* __restrict__ st,
    const float* __restrict__ g, const float* __restrict__ be,
    void* __restrict__ outv) {
  constexpr int CH8 = C / 8, HO = H / 2, WO = W / 2;
  constexpr int HP = NCHW ? HO : HO + 2, WP = NCHW ? WO : WO + 2;
  __shared__ float sA[C], sB[C];
  int tid = threadIdx.x;
  if (tid < C) {
    float mu = st[tid * 2] * invN;
    float var = st[tid * 2 + 1] * invN - mu * mu;
    float sc = g[tid] * rsqrtf(var + 1e-5f);
    sA[tid] = sc;
    sB[tid] = be[tid] - mu * sc;
  }
  __syncthreads();
  const size_t T = (size_t)256 * HP * WP * CH8;
  for (size_t i = (size_t)blockIdx.x * 256 + tid; i < T;
       i += (size_t)gridDim.x * 256) {
    int slot = (int)(i % CH8);
    size_t t = i / CH8;
    int xx = (int)(t % WP);
    t /= WP;
    int yy = (int)(t % HP);
    int b = (int)(t / HP);
    int px, py;
    bool border = false;
    if (NCHW) {
      px = xx;
      py = yy;
    } else {
      px = xx - 1;
      py = yy - 1;
      border = (yy == 0 || yy == HP - 1 || xx == 0 || xx == WP - 1);
    }
    if (border) {
      ((uint4*)outv)[i] = make_uint4(0u, 0u, 0u, 0u);
      continue;
    }
    const uint4* yp = (const uint4*)y;
    size_t i00 = (((size_t)(b * H + 2 * py) * W) + 2 * px) * CH8 + slot;
    uint4 v00 = yp[i00], v01 = yp[i00 + CH8];
    uint4 v10 = yp[i00 + (size_t)W * CH8], v11 = yp[i00 + (size_t)W * CH8 + CH8];
    u32 p00[4] = {v00.x, v00.y, v00.z, v00.w};
    u32 p01[4] = {v01.x, v01.y, v01.z, v01.w};
    u32 p10[4] = {v10.x, v10.y, v10.z, v10.w};
    u32 p11[4] = {v11.x, v11.y, v11.z, v11.w};
    int c0 = slot * 8;
    float r[8];
#pragma unroll
    for (int k = 0; k < 4; k++) {
      int c = c0 + 2 * k;
      float a_ = sA[c], b_ = sB[c], a2 = sA[c + 1], b2 = sB[c + 1];
      float l0 = fmaxf(h2f((u16)(p00[k] & 0xffffu)) * a_ + b_, 0.f);
      float l1 = fmaxf(h2f((u16)(p01[k] & 0xffffu)) * a_ + b_, 0.f);
      float l2 = fmaxf(h2f((u16)(p10[k] & 0xffffu)) * a_ + b_, 0.f);
      float l3 = fmaxf(h2f((u16)(p11[k] & 0xffffu)) * a_ + b_, 0.f);
      float h0 = fmaxf(h2f((u16)(p00[k] >> 16)) * a2 + b2, 0.f);
      float h1 = fmaxf(h2f((u16)(p01[k] >> 16)) * a2 + b2, 0.f);
      float h2 = fmaxf(h2f((u16)(p10[k] >> 16)) * a2 + b2, 0.f);
      float h3 = fmaxf(h2f((u16)(p11[k] >> 16)) * a2 + b2, 0.f);
      r[2 * k] = fmaxf(fmaxf(l0, l1), fmaxf(l2, l3));
      r[2 * k + 1] = fmaxf(fmaxf(h0, h1), fmaxf(h2, h3));
    }
    if (NCHW) {
      u16* of = (u16*)outv;
#pragma unroll
      for (int j = 0; j < 8; j++)
        of[((size_t)(b * C + c0 + j) * HO + py) * WO + px] = f2h(r[j]);
    } else {
      u32 po[4];
#pragma unroll
      for (int k = 0; k < 4; k++)
        po[k] = (u32)f2h(r[2 * k]) | ((u32)f2h(r[2 * k + 1]) << 16);
      ((uint4*)outv)[i] = make_uint4(po[0], po[1], po[2], po[3]);
    }
  }
}

// ---------- split-K MFMA FC ----------
template <int K, int KSPLIT>
__global__ __launch_bounds__(256) void k_fcmfma(const u16* __restrict__ a,
                                                const u16* __restrict__ w,
                                                float* __restrict__ p) {
  constexpr int KCH = K / KSPLIT;
  __shared__ __align__(16) u16 ldsA[128 * 64];
  __shared__ __align__(16) u16 ldsB[64 * 64];
  const int tid = threadIdx.x;
  const int wave = tid >> 6, lane = tid & 63;
  const int m0 = blockIdx.x * 128;
  const int n0 = blockIdx.y * 64;
  const int ks = blockIdx.z;
  const int ss = (lane & 7) ^ (lane >> 3);
  const u16* aptr[4];
#pragma unroll
  for (int q = 0; q < 4; q++)
    aptr[q] = a + (size_t)(m0 + wave * 32 + q * 8 + (lane >> 3)) * K + ss * 8;
  const u16* bptr[2];
#pragma unroll
  for (int q = 0; q < 2; q++)
    bptr[q] = w + (size_t)(n0 + wave * 16 + q * 8 + (lane >> 3)) * K + ss * 8;
  u16* lA = ldsA + wave * 32 * 64;
  u16* lB = ldsB + wave * 16 * 64;
  const int arow0 = wave * 32 + (lane & 15);
  const int nrow = lane & 15;
  const int t0 = lane >> 4, x7 = lane & 7;
  f32x4 acc[2][4] = {};

#pragma unroll 1
  for (int kc = ks * KCH; kc < ks * KCH + KCH; kc += 64) {
    __syncthreads();
#pragma unroll
    for (int q = 0; q < 4; q++) gload16(aptr[q] + kc, lA + q * 512);
#pragma unroll
    for (int q = 0; q < 2; q++) gload16(bptr[q] + kc, lB + q * 512);
    __syncthreads();
#pragma unroll
    for (int h = 0; h < 2; h++) {
      const int sl = (((h << 2) + t0) ^ x7) * 8;
      f16x8 af[2], bf[4];
#pragma unroll
      for (int i = 0; i < 2; i++)
        af[i] = *(const f16x8*)&ldsA[(arow0 + i * 16) * 64 + sl];
#pragma unroll
      for (int j = 0; j < 4; j++)
        bf[j] = *(const f16x8*)&ldsB[(nrow + j * 16) * 64 + sl];
#pragma unroll
      for (int i = 0; i < 2; i++)
#pragma unroll
        for (int j = 0; j < 4; j++)
          acc[i][j] = __builtin_amdgcn_mfma_f32_16x16x32_f16(
              af[i], bf[j], acc[i][j], 0, 0, 0);
    }
  }
  float* po = p + (size_t)ks * (256 * 512);
#pragma unroll
  for (int i = 0; i < 2; i++)
#pragma unroll
    for (int r = 0; r < 4; r++) {
      int m = m0 + wave * 32 + i * 16 + (lane >> 4) * 4 + r;
#pragma unroll
      for (int j = 0; j < 4; j++)
        po[(size_t)m * 512 + n0 + j * 16 + nrow] = acc[i][j][r];
    }
}

// ---------- fused partial-sum + BN1d + relu -> f16 [256][512] ----------
template <int NS>
__global__ __launch_bounds__(256) void k_bn1dfuse(const float* __restrict__ p,
                                                  const float* __restrict__ g,
                                                  const float* __restrict__ be,
                                                  u16* __restrict__ outp) {
  int wave = threadIdx.x >> 6, lane = threadIdx.x & 63;
  int c = blockIdx.x * 4 + wave;
  float v[4] = {};
#pragma unroll 1
  for (int s = 0; s < NS; s++) {
    const float* ps = p + (size_t)s * (256 * 512);
#pragma unroll
    for (int r = 0; r < 4; r++) v[r] += ps[(size_t)(lane + r * 64) * 512 + c];
  }
  float s1 = v[0] + v[1] + v[2] + v[3];
  float s2 = v[0] * v[0] + v[1] * v[1] + v[2] * v[2] + v[3] * v[3];
#pragma unroll
  for (int off = 32; off > 0; off >>= 1) {
    s1 += __shfl_xor(s1, off);
    s2 += __shfl_xor(s2, off);
  }
  float mu = s1 * (1.f / 256.f);
  float var = s2 * (1.f / 256.f) - mu * mu;
  float sc = g[c] * rsqrtf(var + 1e-5f);
  float sh = be[c] - mu * sc;
#pragma unroll
  for (int r = 0; r < 4; r++) {
    float y = fmaxf(v[r] * sc + sh, 0.f);
    outp[(size_t)(lane + r * 64) * 512 + c] = f2h(y);
  }
}

// ---------- fc9 ----------
__global__ __launch_bounds__(256) void k_fc9(const u16* __restrict__ a,
                                             const float* __restrict__ w,
                                             const float* __restrict__ bias,
                                             float* __restrict__ out) {
  int b = blockIdx.x, tid = threadIdx.x;
  int o = tid & 15, ch = tid >> 4;
  float s = 0.f;
  if (o < 10) {
    const u16* ap = a + (size_t)b * 512 + ch * 32;
    const float* wp = w + (size_t)o * 512 + ch * 32;
#pragma unroll
    for (int k = 0; k < 32; k++) s += h2f(ap[k]) * wp[k];
  }
  __shared__ float red[16][17];
  red[ch][o] = s;
  __syncthreads();
  if (tid < 10) {
    float t = bias[tid];
#pragma unroll
    for (int c2 = 0; c2 < 16; c2++) t += red[c2][tid];
    out[b * 10 + tid] = t;
  }
}

// ---------- ALSH: per-filter sumsq + hash dots ----------
__global__ __launch_bounds__(256) void k_w6stats(const float* __restrict__ w6,
                                                 const float* __restrict__ ha,
                                                 float* __restrict__ wstats) {
  int f = blockIdx.x, tid = threadIdx.x;
  const float* wp = w6 + (size_t)f * 2304;
  float ss = 0.f, d0 = 0.f, d1 = 0.f;
#pragma unroll
  for (int k = 0; k < 9; k++) {
    float v = wp[k * 256 + tid];
    ss += v * v;
    d0 += v * ha[k * 256 + tid];
    d1 += v * ha[2306 + k * 256 + tid];
  }
  for (int off = 32; off > 0; off >>= 1) {
    ss += __shfl_down(ss, off);
    d0 += __shfl_down(d0, off);
    d1 += __shfl_down(d1, off);
  }
  __shared__ float r[4][3];
  int wv = tid >> 6, ln = tid & 63;
  if (ln == 0) {
    r[wv][0] = ss;
    r[wv][1] = d0;
    r[wv][2] = d1;
  }
  __syncthreads();
  if (tid == 0) {
    float a0 = 0.f, a1 = 0.f, a2 = 0.f;
    for (int i = 0; i < 4; i++) {
      a0 += r[i][0];
      a1 += r[i][1];
      a2 += r[i][2];
    }
    wstats[f * 4 + 0] = a0;
    wstats[f * 4 + 1] = a1;
    wstats[f * 4 + 2] = a2;
  }
}

// ---------- ALSH: final mask ----------
__global__ __launch_bounds__(256) void k_mask(const float* __restrict__ wstats,
                                              const float* __restrict__ qstats,
                                              const float* __restrict__ ha,
                                              float invN,
                                              float* __restrict__ mask) {
  int tid = threadIdx.x;
  __shared__ float red[256];
  float n2 = wstats[tid * 4];
  red[tid] = n2;
  __syncthreads();
  for (int off = 128; off > 0; off >>= 1) {
    if (tid < off) red[tid] = fmaxf(red[tid], red[tid + off]);
    __syncthreads();
  }
  float maxn2 = red[0];
  float qm = qstats[tid] * invN;
  float h0 = 0.f, h1 = 0.f;
#pragma unroll
  for (int k = 0; k < 9; k++) {
    h0 += ha[k * 256 + tid];
    h1 += ha[2306 + k * 256 + tid];
  }
  __shared__ float r0[256], r1[256];
  r0[tid] = qm * h0;
  r1[tid] = qm * h1;
  __syncthreads();
  for (int off = 128; off > 0; off >>= 1) {
    if (tid < off) {
      r0[tid] += r0[tid + off];
      r1[tid] += r1[tid + off];
    }
    __syncthreads();
  }
  float qd0 = r0[0], qd1 = r1[0];
  float s = U_CONST / sqrtf(maxn2);
  float ns2 = s * s * wstats[tid * 4];
  float v0 = s * wstats[tid * 4 + 1] + ns2 * ha[2304] + ns2 * ns2 * ha[2305];
  float v1 = s * wstats[tid * 4 + 2] + ns2 * ha[2306 + 2304] +
             ns2 * ns2 * ha[2306 + 2305];
  bool bf0 = v0 > 0.f, bf1 = v1 > 0.f;
  bool bq0 = qd0 > 0.f, bq1 = qd1 > 0.f;
  mask[tid] = (bf0 == bq0 && bf1 == bq1) ? 1.f : 0.f;
}

// ======================================================================
extern "C" void kernel_launch(void* const* d_in, const int* in_sizes, int n_in,
                              void* d_out, int out_size, void* d_ws,
                              size_t ws_size, hipStream_t stream) {
  (void)in_sizes; (void)n_in; (void)out_size; (void)ws_size;
  const float* x = (const float*)d_in[0];
  const float* w1 = (const float*)d_in[1];
  const float* b1 = (const float*)d_in[2];
  const float* g1 = (const float*)d_in[3];
  const float* be1 = (const float*)d_in[4];
  const float* w2 = (const float*)d_in[5];
  const float* b2 = (const float*)d_in[6];
  const float* g2 = (const float*)d_in[7];
  const float* be2 = (const float*)d_in[8];
  const float* w3 = (const float*)d_in[9];
  const float* b3 = (const float*)d_in[10];
  const float* g3 = (const float*)d_in[11];
  const float* be3 = (const float*)d_in[12];
  const float* w4 = (const float*)d_in[13];
  const float* b4 = (const float*)d_in[14];
  const float* g4 = (const float*)d_in[15];
  const float* be4 = (const float*)d_in[16];
  const float* w5 = (const float*)d_in[17];
  const float* b5 = (const float*)d_in[18];
  const float* g5 = (const float*)d_in[19];
  const float* be5 = (const float*)d_in[20];
  const float* w6 = (const float*)d_in[21];
  const float* b6 = (const float*)d_in[22];
  const float* g6 = (const float*)d_in[23];
  const float* be6 = (const float*)d_in[24];
  const float* hash_a = (const float*)d_in[25];
  const float* fc7_w = (const float*)d_in[26];
  const float* g7 = (const float*)d_in[28];
  const float* be7 = (const float*)d_in[29];
  const float* fc8_w = (const float*)d_in[30];
  const float* g8 = (const float*)d_in[32];
  const float* be8 = (const float*)d_in[33];
  const float* fc9_w = (const float*)d_in[34];
  const float* fc9_b = (const float*)d_in[35];

  char* wsb = (char*)d_ws;
  float* stats = (float*)(wsb + OFFB_STATS);
  float* wstats = (float*)(wsb + OFFB_WSTAT);
  float* maskb = (float*)(wsb + OFFB_MASK);
  u16* fcin = (u16*)(wsb + OFFB_FCIN);
  u16* w7t = (u16*)(wsb + OFFB_W7T);
  u16* w8t = (u16*)(wsb + OFFB_W8T);
  float* p7 = (float*)(wsb + OFFB_P7);
  float* p8 = (float*)(wsb + OFFB_P8);
  u16* a7 = (u16*)(wsb + OFFB_A7);
  u16* a8 = (u16*)(wsb + OFFB_A8);
  float* part = (float*)(wsb + OFFB_PART);
  float* qpart = (float*)(wsb + OFFB_QPART);
  u16* wt2 = (u16*)(wsb + OFFB_WT2);
  u16* wt3 = (u16*)(wsb + OFFB_WT3);
  u16* wt4 = (u16*)(wsb + OFFB_WT4);
  u16* wt5 = (u16*)(wsb + OFFB_WT5);
  u16* wt6 = (u16*)(wsb + OFFB_WT6);
  u16* slab1 = (u16*)(wsb + OFFB_SLAB1);
  u16* slab2 = (u16*)(wsb + OFFB_SLAB2);
  float* outp = (float*)d_out;

  k_wprep<<<2048, 256, 0, stream>>>(w2, w3, w4, w5, w6, fc7_w, fc8_w, wt2, wt3,
                                    wt4, wt5, wt6, w7t, w8t);
  k_w6stats<<<256, 256, 0, stream>>>(w6, hash_a, wstats);

  // layer 1 (reads NCHW x directly)
  k_conv1<<<4096, 256, 0, stream>>>(x, w1, b1, slab1, part);
  k_redstat<<<64, 256, 0, stream>>>(part, stats + 0, 4096, 64);
  k_bnrelu_pad<64, 32, 32, false><<<1024, 256, 0, stream>>>(
      slab1, 1.f / 262144.f, stats + 0, g1, be1, slab2, nullptr);
  // layer 2: BM=256, BN=64
  k_cmfma<64, 64, 32, 32, 4, 1, false><<<dim3(1024, 1), 256, 0, stream>>>(
      slab2, wt2, b2, nullptr, slab1, part);
  k_redstat<<<64, 256, 0, stream>>>(part, stats + 512, 1024, 64);
  k_bnpool<64, 32, 32, false><<<512, 256, 0, stream>>>(
      slab1, 1.f / 262144.f, stats + 512, g2, be2, slab2);
  // layer 3: BM=128, BN=128
  k_cmfma<64, 128, 16, 16, 2, 2, false><<<dim3(512, 1), 256, 0, stream>>>(
      slab2, wt3, b3, nullptr, slab1, part);
  k_redstat<<<128, 256, 0, stream>>>(part, stats + 1024, 512, 128);
  k_bnrelu_pad<128, 16, 16, false><<<1024, 256, 0, stream>>>(
      slab1, 1.f / 65536.f, stats + 1024, g3, be3, slab2, nullptr);
  // layer 4
  k_cmfma<128, 128, 16, 16, 2, 2, false><<<dim3(512, 1), 256, 0, stream>>>(
      slab2, wt4, b4, nullptr, slab1, part);
  k_redstat<<<128, 256, 0, stream>>>(part, stats + 1536, 512, 128);
  k_bnpool<128, 16, 16, false><<<512, 256, 0, stream>>>(
      slab1, 1.f / 65536.f, stats + 1536, g4, be4, slab2);
  // layer 5
  k_cmfma<128, 256, 8, 8, 2, 2, false><<<dim3(128, 2), 256, 0, stream>>>(
      slab2, wt5, b5, nullptr, slab1, part);
  k_redstat<<<256, 256, 0, stream>>>(part, stats + 2048, 128, 256);
  k_bnrelu_pad<256, 8, 8, true><<<1024, 256, 0, stream>>>(
      slab1, 1.f / 16384.f, stats + 2048, g5, be5, slab2, qpart);
  // ALSH mask
  k_qred<<<256, 256, 0, stream>>>(qpart, stats + 3072, 1024);
  k_mask<<<1, 256, 0, stream>>>(wstats, stats + 3072, hash_a, 1.f / 16384.f,
                                maskb);
  // layer 6 (masked)
  k_cmfma<256, 256, 8, 8, 2, 2, true><<<dim3(128, 2), 256, 0, stream>>>(
      slab2, wt6, b6, maskb, slab1, part);
  k_redstat<<<256, 256, 0, stream>>>(part, stats + 2560, 128, 256);
  k_bnpool<256, 8, 8, true><<<512, 256, 0, stream>>>(
      slab1, 1.f / 16384.f, stats + 2560, g6, be6, fcin);
  // FC head
  k_fcmfma<4096, 16><<<dim3(2, 8, 16), 256, 0, stream>>>(fcin, w7t, p7);
  k_bn1dfuse<16><<<128, 256, 0, stream>>>(p7, g7, be7, a7);
  k_fcmfma<512, 8><<<dim3(2, 8, 8), 256, 0, stream>>>(a7, w8t, p8);
  k_bn1dfuse<8><<<128, 256, 0, stream>>>(p8, g8, be8, a8);
  k_fc9<<<256, 256, 0, stream>>>(a8, fc9_w, fc9_b, outp);
}